// Round 6
// baseline (711.212 us; speedup 1.0000x reference)
//
#include <hip/hip_runtime.h>
#include <hip/hip_bf16.h>
#include <math.h>

// ---------------------------------------------------------------------------
// SelfAttn2d: out = x + gamma * (V @ softmax(Q K^T / sqrt(32))^T)
// B=4, C=256, N=4096, D=32.
// Round 6: R5 + __launch_bounds__(512, 2) everywhere. R5's VGPR_Count=64
// shows the allocator targeted 8 waves/EU and AGPR-spilled the inner loop
// (VALUBusy 25% = v_accvgpr traffic, MfmaUtil 3%). Min-waves=2 -> ~256 VGPR
// budget, no spill, 2 waves/SIMD.
// ---------------------------------------------------------------------------

#define NPOS 4096
#define PSTR 136   // P row stride (bf16): 272B = 17*16B -> aligned b128, odd word stride
#define XSTR 264   // XT row stride (bf16): 528B = 33*16B -> aligned b128

typedef __bf16 bf16x8 __attribute__((ext_vector_type(8)));
typedef float  f32x16 __attribute__((ext_vector_type(16)));

static __device__ inline unsigned int pk2(float a, float b) {
    union { __hip_bfloat16 h[2]; unsigned int u; } x;
    x.h[0] = __float2bfloat16(a);
    x.h[1] = __float2bfloat16(b);
    return x.u;
}
static __device__ inline bf16x8 cvt8(float4 a, float4 b) {
    union { bf16x8 v; unsigned int u[4]; } t;
    t.u[0] = pk2(a.x, a.y); t.u[1] = pk2(a.z, a.w);
    t.u[2] = pk2(b.x, b.y); t.u[3] = pk2(b.z, b.w);
    return t.v;
}

// ---------------------------------------------------------------------------
// sigma_all: block 0 -> sigma(wq), 1 -> sigma(wk), 2 -> sigma(wv). 512 thr.
// ---------------------------------------------------------------------------
__global__ __launch_bounds__(512, 2) void sigma_all(const float* __restrict__ wq,
                                                    const float* __restrict__ wk,
                                                    const float* __restrict__ wv,
                                                    float* __restrict__ scal) {
    __shared__ __align__(16) __hip_bfloat16 Wsh[256 * XSTR];
    __shared__ float red[512];
    __shared__ float trsh;
    __shared__ float xv[256];

    int t = threadIdx.x;

    if (blockIdx.x < 2) {
        const float* w = (blockIdx.x == 0) ? wq : wk;
        float* F  = (float*)Wsh;
        float* Ws = F;                 // [32][257]
        float* G  = F + 32 * 257;
        float* A  = G + 32 * 33;
        float* Bt = A + 32 * 33;
        float* xq = Bt + 32 * 33;
        float* yq = xq + 32;

        if (t < 256) {
            for (int i = 0; i < 32; i++) {
                int idx = t + 256 * i;
                Ws[(idx >> 8) * 257 + (idx & 255)] = w[idx];
            }
        }
        __syncthreads();
        if (t < 256) {
            for (int i = 0; i < 4; i++) {
                int id = t + 256 * i;
                int r = id >> 5, cc = id & 31;
                float s = 0.f;
                for (int c = 0; c < 256; c++) s += Ws[r * 257 + c] * Ws[cc * 257 + c];
                G[r * 33 + cc] = s;
                A[r * 33 + cc] = s;
            }
        }
        __syncthreads();
        for (int sq = 0; sq < 8; sq++) {
            if (t == 0) {
                float tr = 0.f;
                for (int i = 0; i < 32; i++) tr += A[i * 33 + i];
                trsh = 1.0f / tr;
            }
            __syncthreads();
            float invt = trsh;
            if (t < 256) {
                for (int i = 0; i < 4; i++) {
                    int id = t + 256 * i;
                    int r = id >> 5, cc = id & 31;
                    float s = 0.f;
                    #pragma unroll
                    for (int k2 = 0; k2 < 32; k2++) s += A[r * 33 + k2] * A[cc * 33 + k2];
                    Bt[r * 33 + cc] = s * invt * invt;
                }
            }
            __syncthreads();
            if (t < 256) {
                for (int i = 0; i < 4; i++) {
                    int id = t + 256 * i;
                    A[(id >> 5) * 33 + (id & 31)] = Bt[(id >> 5) * 33 + (id & 31)];
                }
            }
            __syncthreads();
        }
        if (t < 32) xq[t] = 1.0f + 0.01f * t;
        __syncthreads();
        for (int it = 0; it < 4; it++) {
            if (t < 32) {
                float y = 0.f;
                #pragma unroll
                for (int j = 0; j < 32; j++) y += A[t * 33 + j] * xq[j];
                yq[t] = y;
            }
            __syncthreads();
            if (t < 32) {
                float ss = 0.f;
                #pragma unroll
                for (int j = 0; j < 32; j++) ss += yq[j] * yq[j];
                xq[t] = yq[t] * rsqrtf(ss);
            }
            __syncthreads();
        }
        if (t == 0) {
            float lam = 0.f;
            for (int i = 0; i < 32; i++) {
                float y = 0.f;
                for (int j = 0; j < 32; j++) y += G[i * 33 + j] * xq[j];
                lam += xq[i] * y;
            }
            scal[blockIdx.x] = rsqrtf(lam);
        }
        return;
    }

    // v path: 256x256 Gram^64 chain on MFMA in LDS
    int wave = t >> 6, lane = t & 63, lo = lane & 31, hi = lane >> 5;
    int p = wave >> 1;
    int q = wave & 1;

    for (int i = 0; i < 128; i++) {
        int idx = t + 512 * i;
        Wsh[(idx >> 8) * XSTR + (idx & 255)] = __float2bfloat16(wv[idx]);
    }
    __syncthreads();

    for (int round = 0; round < 7; round++) {
        f32x16 c[2][4];
        #pragma unroll
        for (int mt = 0; mt < 2; mt++)
            #pragma unroll
            for (int j = 0; j < 4; j++)
                #pragma unroll
                for (int r = 0; r < 16; r++) c[mt][j][r] = 0.f;

        for (int kc = 0; kc < 16; kc++) {
            bf16x8 af[2], bfj[4];
            #pragma unroll
            for (int mt = 0; mt < 2; mt++)
                af[mt] = *(const bf16x8*)&Wsh[((2 * p + mt) * 32 + lo) * XSTR + kc * 16 + hi * 8];
            #pragma unroll
            for (int j = 0; j < 4; j++)
                bfj[j] = *(const bf16x8*)&Wsh[((4 * q + j) * 32 + lo) * XSTR + kc * 16 + hi * 8];
            #pragma unroll
            for (int mt = 0; mt < 2; mt++)
                #pragma unroll
                for (int j = 0; j < 4; j++)
                    c[mt][j] = __builtin_amdgcn_mfma_f32_32x32x16_bf16(af[mt], bfj[j], c[mt][j], 0, 0, 0);
        }

        float dsum = 0.f;
        #pragma unroll
        for (int mt = 0; mt < 2; mt++) {
            int Tm = 2 * p + mt;
            if ((Tm >> 2) == q) {
                int j = Tm - 4 * q;
                #pragma unroll
                for (int r = 0; r < 16; r++) {
                    int row = (r & 3) + 8 * (r >> 2) + 4 * hi;
                    if (row == lo) dsum += c[mt][j][r];
                }
            }
        }
        red[t] = dsum;
        __syncthreads();
        for (int s2 = 256; s2 > 0; s2 >>= 1) {
            if (t < s2) red[t] += red[t + s2];
            __syncthreads();
        }
        float invt = 1.0f / red[0];
        __syncthreads();

        #pragma unroll
        for (int mt = 0; mt < 2; mt++)
            #pragma unroll
            for (int j = 0; j < 4; j++)
                #pragma unroll
                for (int r = 0; r < 16; r++) {
                    int row = (2 * p + mt) * 32 + (r & 3) + 8 * (r >> 2) + 4 * hi;
                    int col = (4 * q + j) * 32 + lo;
                    Wsh[row * XSTR + col] = __float2bfloat16(c[mt][j][r] * invt);
                }
        __syncthreads();
    }

    if (t < 256) xv[t] = 1.0f + 0.01f * t;
    __syncthreads();
    for (int it = 0; it < 8; it++) {
        float y = 0.f;
        if (t < 256) {
            for (int ch = 0; ch < 32; ch++) {
                bf16x8 a = *(const bf16x8*)&Wsh[t * XSTR + ch * 8];
                #pragma unroll
                for (int e = 0; e < 8; e++) y += (float)a[e] * xv[ch * 8 + e];
            }
        }
        red[t] = (t < 256) ? y * y : 0.f;
        __syncthreads();
        for (int s2 = 256; s2 > 0; s2 >>= 1) {
            if (t < s2) red[t] += red[t + s2];
            __syncthreads();
        }
        if (t == 0) trsh = rsqrtf(red[0]);
        __syncthreads();
        if (t < 256) xv[t] = y * trsh;
        __syncthreads();
    }

    float z = 0.f;
    if (t < 256) {
        for (int i = 0; i < 256; i++) z += wv[i * 256 + t] * xv[i];
    }
    red[t] = (t < 256) ? z * z : 0.f;
    __syncthreads();
    for (int s2 = 256; s2 > 0; s2 >>= 1) {
        if (t < s2) red[t] += red[t + s2];
        __syncthreads();
    }
    if (t == 0) scal[2] = rsqrtf(red[0]);
}

// ---------------------------------------------------------------------------
// proj: fused MFMA projection. Grid (64 n-tiles, 4 b), 512 thr (8 waves).
// Stage X^T tile [64 n][256 c] bf16 in LDS. Wave w: v j-tile w (e=32w..32w+32)
// x 2 i-tiles; waves 0..3 additionally one q/k fragment each.
// Outputs: v[b][e][n] (packed uint2 stores), qT/kT[b][n][32] via LDS transpose.
// ---------------------------------------------------------------------------
__global__ __launch_bounds__(512, 2) void proj(const float* __restrict__ x,
                                               const float* __restrict__ wq,
                                               const float* __restrict__ wk,
                                               const float* __restrict__ wv,
                                               __hip_bfloat16* __restrict__ qT,
                                               __hip_bfloat16* __restrict__ kT,
                                               __hip_bfloat16* __restrict__ v) {
    __shared__ __align__(16) __hip_bfloat16 XT[64 * XSTR];    // 33.8 KB
    __shared__ __align__(16) __hip_bfloat16 Tq[4][32 * 40];   // 10 KB transpose buf

    int t = threadIdx.x;
    int wave = t >> 6, lane = t & 63, lo = lane & 31, hi = lane >> 5;
    int n0 = blockIdx.x * 64;
    int b = blockIdx.y;
    const float* xb = x + ((size_t)b << 20);

    // stage: XT[n][c] = bf16(x[c][n0+n]); 8 c-groups of 32
    {
        int nl = t & 63, cg = t >> 6;
        #pragma unroll 8
        for (int i = 0; i < 32; i++) {
            int c = cg * 32 + i;
            XT[nl * XSTR + c] = __float2bfloat16(xb[(size_t)c * NPOS + n0 + nl]);
        }
    }
    __syncthreads();

    f32x16 accv[2], accq;
    #pragma unroll
    for (int it = 0; it < 2; it++)
        #pragma unroll
        for (int r = 0; r < 16; r++) accv[it][r] = 0.f;
    #pragma unroll
    for (int r = 0; r < 16; r++) accq[r] = 0.f;

    const float* wvrow = wv + (size_t)(wave * 32 + lo) * 256 + hi * 8;
    const float* wqkrow = ((wave < 2) ? wq : wk) + (size_t)lo * 256 + hi * 8;
    int qk_it = wave & 1;  // i-tile for the qk fragment (waves 0..3)

    for (int kc = 0; kc < 16; kc++) {
        bf16x8 af0 = *(const bf16x8*)&XT[lo * XSTR + kc * 16 + hi * 8];
        bf16x8 af1 = *(const bf16x8*)&XT[(32 + lo) * XSTR + kc * 16 + hi * 8];
        float4 wa = *(const float4*)(wvrow + kc * 16);
        float4 wb = *(const float4*)(wvrow + kc * 16 + 4);
        bf16x8 bfv = cvt8(wa, wb);
        accv[0] = __builtin_amdgcn_mfma_f32_32x32x16_bf16(af0, bfv, accv[0], 0, 0, 0);
        accv[1] = __builtin_amdgcn_mfma_f32_32x32x16_bf16(af1, bfv, accv[1], 0, 0, 0);
        if (wave < 4) {
            float4 qa = *(const float4*)(wqkrow + kc * 16);
            float4 qb = *(const float4*)(wqkrow + kc * 16 + 4);
            bf16x8 bfq = cvt8(qa, qb);
            accq = __builtin_amdgcn_mfma_f32_32x32x16_bf16(qk_it ? af1 : af0, bfq, accq, 0, 0, 0);
        }
    }

    // ---- v epilogue: C col = e-local(lo), row = n pattern. uint2 packed stores.
    __hip_bfloat16* vbb = v + ((size_t)b << 20) + (size_t)(wave * 32 + lo) * NPOS + n0;
    #pragma unroll
    for (int it = 0; it < 2; it++)
        #pragma unroll
        for (int g = 0; g < 4; g++) {
            uint2 pk;
            pk.x = pk2(accv[it][4 * g + 0], accv[it][4 * g + 1]);
            pk.y = pk2(accv[it][4 * g + 2], accv[it][4 * g + 3]);
            *(uint2*)(vbb + it * 32 + 8 * g + 4 * hi) = pk;
        }

    // ---- qk epilogue: transpose 32n x 32d through LDS, coalesced b128 out.
    if (wave < 4) {
        __hip_bfloat16* T = Tq[wave];
        #pragma unroll
        for (int r = 0; r < 16; r++) {
            int n = (r & 3) + 8 * (r >> 2) + 4 * hi;
            T[n * 40 + lo] = __float2bfloat16(accq[r]);
        }
    }
    __syncthreads();  // uniform barrier: transpose buffers visible
    if (wave < 4) {
        __hip_bfloat16* T = Tq[wave];
        __hip_bfloat16* dst = ((wave < 2) ? qT : kT) + ((size_t)b << 17)
                              + (size_t)(n0 + qk_it * 32) * 32;
        #pragma unroll
        for (int p = 0; p < 2; p++) {
            int idx = p * 64 + lane;
            int n = idx >> 2, quad = idx & 3;
            bf16x8 row = *(const bf16x8*)&T[n * 40 + quad * 8];
            *(bf16x8*)(dst + (size_t)n * 32 + quad * 8) = row;
        }
    }
}

// ---------------------------------------------------------------------------
// MFMA flash attention. 512 thr (8 waves), grid 256 (64 m-tiles x 4 b).
// n-step 128. Wave w: S^T quadrant (mtile=w>>2, ntile=w&3) -> P[m][n] LDS;
// PV: e-rows [32w,32w+32), 8x(V global b128 + 2 P b128 + 2 MFMA).
// launch_bounds(512,2): ~256 VGPR budget -> no AGPR-spill of vf/kf/sv.
// No max-subtraction (spectral norm bounds logits << fp32 exp range).
// ---------------------------------------------------------------------------
__global__ __launch_bounds__(512, 2) void attn_mfma(const float* __restrict__ x,
                                                    const __hip_bfloat16* __restrict__ qT,
                                                    const __hip_bfloat16* __restrict__ kT,
                                                    const __hip_bfloat16* __restrict__ v,
                                                    const float* __restrict__ scal,
                                                    const float* __restrict__ gam,
                                                    float* __restrict__ out) {
    __shared__ __align__(16) __hip_bfloat16 Plds[64 * PSTR];  // 17.4 KB
    __shared__ float Lpart[8][32];

    int t = threadIdx.x;
    int wave = t >> 6, lane = t & 63;
    int lo = lane & 31, hi = lane >> 5;

    // XCD swizzle: batch pinned to XCD pair
    int blk = blockIdx.x;
    int x8 = blk & 7;
    int b = x8 >> 1;
    int m0 = (((x8 & 1) << 5) + (blk >> 3)) << 6;

    const __hip_bfloat16* qTb = qT + ((size_t)b << 17);
    const __hip_bfloat16* kTb = kT + ((size_t)b << 17);
    const __hip_bfloat16* vb  = v  + ((size_t)b << 20);

    int mtile = wave >> 2, ntile = wave & 3;
    float qkscale = scal[0] * scal[1] * 0.17677669529663687f;

    // persistent Q B-frag (this wave's m-tile)
    const __hip_bfloat16* qrow = qTb + (size_t)(m0 + mtile * 32 + lo) * 32 + hi * 8;
    bf16x8 qf0 = *(const bf16x8*)(qrow);
    bf16x8 qf1 = *(const bf16x8*)(qrow + 16);

    const __hip_bfloat16* kaddr = kTb + (size_t)(ntile * 32 + lo) * 32 + hi * 8;
    const __hip_bfloat16* vaddr = vb + (size_t)(wave * 32 + lo) * NPOS + hi * 8;

    f32x16 acc[2];
    #pragma unroll
    for (int mt = 0; mt < 2; mt++)
        #pragma unroll
        for (int r = 0; r < 16; r++) acc[mt][r] = 0.f;
    float l_acc = 0.f;

    bf16x8 kf[2][2];
    kf[0][0] = *(const bf16x8*)(kaddr);
    kf[0][1] = *(const bf16x8*)(kaddr + 16);

    for (int s = 0; s < 32; s++) {
        int cur = s & 1, nxt = cur ^ 1;
        int n0 = 128 * s;

        // S^T = K x Q (rows n, cols m)
        f32x16 sv;
        #pragma unroll
        for (int r = 0; r < 16; r++) sv[r] = 0.f;
        sv = __builtin_amdgcn_mfma_f32_32x32x16_bf16(kf[cur][0], qf0, sv, 0, 0, 0);
        sv = __builtin_amdgcn_mfma_f32_32x32x16_bf16(kf[cur][1], qf1, sv, 0, 0, 0);

        // prefetch next K frag
        if (s < 31) {
            const __hip_bfloat16* ka = kaddr + (size_t)(n0 + 128) * 32;
            kf[nxt][0] = *(const bf16x8*)(ka);
            kf[nxt][1] = *(const bf16x8*)(ka + 16);
        }
        // preload this step's V frags (latency hides under exp+barriers)
        bf16x8 vf[8];
        #pragma unroll
        for (int kc = 0; kc < 8; kc++)
            vf[kc] = *(const bf16x8*)(vaddr + n0 + kc * 16);

        __syncthreads();  // prior PV reads of Plds done
        {
            int mrow = mtile * 32 + lo;
            #pragma unroll
            for (int g = 0; g < 4; g++) {
                float p0 = __expf(sv[4 * g + 0] * qkscale);
                float p1 = __expf(sv[4 * g + 1] * qkscale);
                float p2 = __expf(sv[4 * g + 2] * qkscale);
                float p3 = __expf(sv[4 * g + 3] * qkscale);
                l_acc += (p0 + p1) + (p2 + p3);
                uint2 pk;
                pk.x = pk2(p0, p1);
                pk.y = pk2(p2, p3);
                *(uint2*)(&Plds[mrow * PSTR + ntile * 32 + 8 * g + 4 * hi]) = pk;
            }
        }
        __syncthreads();  // P ready

        // PV: D[e][m] += V x P
        #pragma unroll
        for (int kc = 0; kc < 8; kc++) {
            bf16x8 pf0 = *(const bf16x8*)(&Plds[lo * PSTR + kc * 16 + hi * 8]);
            bf16x8 pf1 = *(const bf16x8*)(&Plds[(32 + lo) * PSTR + kc * 16 + hi * 8]);
            acc[0] = __builtin_amdgcn_mfma_f32_32x32x16_bf16(vf[kc], pf0, acc[0], 0, 0, 0);
            acc[1] = __builtin_amdgcn_mfma_f32_32x32x16_bf16(vf[kc], pf1, acc[1], 0, 0, 0);
        }
    }

    // L partials: lane^32 holds same m, other n-rows of the quadrant
    float lsum = l_acc + __shfl_xor(l_acc, 32, 64);
    if (lane < 32) Lpart[wave][lane] = lsum;
    __syncthreads();

    // epilogue: out = x + gamma*sig_v^-1 * acc / L
    float gs = gam[0] * scal[2];
    const float* xb = x + ((size_t)b << 20);
    float* ob = out + ((size_t)b << 20);
    #pragma unroll
    for (int mt = 0; mt < 2; mt++) {
        float L = Lpart[4 * mt][lo] + Lpart[4 * mt + 1][lo] +
                  Lpart[4 * mt + 2][lo] + Lpart[4 * mt + 3][lo];
        float f = gs / L;
        int m = m0 + mt * 32 + lo;
        #pragma unroll
        for (int r = 0; r < 16; r++) {
            int e = wave * 32 + (r & 3) + 8 * (r >> 2) + 4 * hi;
            size_t idx = (size_t)e * NPOS + m;
            ob[idx] = xb[idx] + f * acc[mt][r];
        }
    }
}

// ---------------------------------------------------------------------------
extern "C" void kernel_launch(void* const* d_in, const int* in_sizes, int n_in,
                              void* d_out, int out_size, void* d_ws, size_t ws_size,
                              hipStream_t stream) {
    const float* x     = (const float*)d_in[0];
    const float* wq    = (const float*)d_in[1];
    const float* wk    = (const float*)d_in[2];
    const float* wv    = (const float*)d_in[3];
    const float* gamma = (const float*)d_in[4];
    float* out = (float*)d_out;

    char* wsb = (char*)d_ws;
    float* scal = (float*)wsb;                          // [0..63]
    __hip_bfloat16* qT = (__hip_bfloat16*)(wsb + 256);
    __hip_bfloat16* kT = qT + (size_t)4 * NPOS * 32;
    __hip_bfloat16* vp = kT + (size_t)4 * NPOS * 32;    // 4*256*4096 bf16

    proj<<<dim3(64, 4), 512, 0, stream>>>(x, wq, wk, wv, qT, kT, vp);
    sigma_all<<<3, 512, 0, stream>>>(wq, wk, wv, scal);
    attn_mfma<<<256, 512, 0, stream>>>(x, qT, kT, vp, scal, gamma, out);
}

// Round 7
// 313.968 us; speedup vs baseline: 2.2652x; 2.2652x over previous
//
#include <hip/hip_runtime.h>
#include <hip/hip_bf16.h>
#include <math.h>

// ---------------------------------------------------------------------------
// SelfAttn2d: out = x + gamma * (V @ softmax(Q K^T / sqrt(32))^T)
// B=4, C=256, N=4096, D=32.
// Round 7: revert attn to the R2-proven 256-thr/4-wave loop (VGPR 132,
// 127us codegen) and gain TLP via n-split: grid 512 (2 n-halves), partial
// unnormalized O (bf16) + L to ws, merged by a new HBM-bound reduce kernel.
// R5/R6's 512-thr restructure triggered a 64-VGPR allocation with AGPR-move
// bloat (VALUBusy 25%, MfmaUtil 3%) -- abandoned.
// ---------------------------------------------------------------------------

#define NPOS 4096
#define XSTR 264   // bf16 row stride for 256x256 LDS matrix (33*16B)

typedef __bf16 bf16x8 __attribute__((ext_vector_type(8)));
typedef float  f32x16 __attribute__((ext_vector_type(16)));

static __device__ inline unsigned int pk2(float a, float b) {
    union { __hip_bfloat16 h[2]; unsigned int u; } x;
    x.h[0] = __float2bfloat16(a);
    x.h[1] = __float2bfloat16(b);
    return x.u;
}
static __device__ inline bf16x8 cvt8(float4 a, float4 b) {
    union { bf16x8 v; unsigned int u[4]; } t;
    t.u[0] = pk2(a.x, a.y); t.u[1] = pk2(a.z, a.w);
    t.u[2] = pk2(b.x, b.y); t.u[3] = pk2(b.z, b.w);
    return t.v;
}
static __device__ inline float b2f(unsigned short u) {
    union { float f; unsigned int i; } x;
    x.i = ((unsigned int)u) << 16;
    return x.f;
}

// ---------------------------------------------------------------------------
// sigma_all: block 0 -> sigma(wq), 1 -> sigma(wk), 2 -> sigma(wv). 512 thr.
// (unchanged -- verified correct)
// ---------------------------------------------------------------------------
__global__ __launch_bounds__(512, 2) void sigma_all(const float* __restrict__ wq,
                                                    const float* __restrict__ wk,
                                                    const float* __restrict__ wv,
                                                    float* __restrict__ scal) {
    __shared__ __align__(16) __hip_bfloat16 Wsh[256 * XSTR];
    __shared__ float red[512];
    __shared__ float trsh;
    __shared__ float xv[256];

    int t = threadIdx.x;

    if (blockIdx.x < 2) {
        const float* w = (blockIdx.x == 0) ? wq : wk;
        float* F  = (float*)Wsh;
        float* Ws = F;                 // [32][257]
        float* G  = F + 32 * 257;
        float* A  = G + 32 * 33;
        float* Bt = A + 32 * 33;
        float* xq = Bt + 32 * 33;
        float* yq = xq + 32;

        if (t < 256) {
            for (int i = 0; i < 32; i++) {
                int idx = t + 256 * i;
                Ws[(idx >> 8) * 257 + (idx & 255)] = w[idx];
            }
        }
        __syncthreads();
        if (t < 256) {
            for (int i = 0; i < 4; i++) {
                int id = t + 256 * i;
                int r = id >> 5, cc = id & 31;
                float s = 0.f;
                for (int c = 0; c < 256; c++) s += Ws[r * 257 + c] * Ws[cc * 257 + c];
                G[r * 33 + cc] = s;
                A[r * 33 + cc] = s;
            }
        }
        __syncthreads();
        for (int sq = 0; sq < 8; sq++) {
            if (t == 0) {
                float tr = 0.f;
                for (int i = 0; i < 32; i++) tr += A[i * 33 + i];
                trsh = 1.0f / tr;
            }
            __syncthreads();
            float invt = trsh;
            if (t < 256) {
                for (int i = 0; i < 4; i++) {
                    int id = t + 256 * i;
                    int r = id >> 5, cc = id & 31;
                    float s = 0.f;
                    #pragma unroll
                    for (int k2 = 0; k2 < 32; k2++) s += A[r * 33 + k2] * A[cc * 33 + k2];
                    Bt[r * 33 + cc] = s * invt * invt;
                }
            }
            __syncthreads();
            if (t < 256) {
                for (int i = 0; i < 4; i++) {
                    int id = t + 256 * i;
                    A[(id >> 5) * 33 + (id & 31)] = Bt[(id >> 5) * 33 + (id & 31)];
                }
            }
            __syncthreads();
        }
        if (t < 32) xq[t] = 1.0f + 0.01f * t;
        __syncthreads();
        for (int it = 0; it < 4; it++) {
            if (t < 32) {
                float y = 0.f;
                #pragma unroll
                for (int j = 0; j < 32; j++) y += A[t * 33 + j] * xq[j];
                yq[t] = y;
            }
            __syncthreads();
            if (t < 32) {
                float ss = 0.f;
                #pragma unroll
                for (int j = 0; j < 32; j++) ss += yq[j] * yq[j];
                xq[t] = yq[t] * rsqrtf(ss);
            }
            __syncthreads();
        }
        if (t == 0) {
            float lam = 0.f;
            for (int i = 0; i < 32; i++) {
                float y = 0.f;
                for (int j = 0; j < 32; j++) y += G[i * 33 + j] * xq[j];
                lam += xq[i] * y;
            }
            scal[blockIdx.x] = rsqrtf(lam);
        }
        return;
    }

    // v path: 256x256 Gram^64 chain on MFMA in LDS
    int wave = t >> 6, lane = t & 63, lo = lane & 31, hi = lane >> 5;
    int p = wave >> 1;
    int q = wave & 1;

    for (int i = 0; i < 128; i++) {
        int idx = t + 512 * i;
        Wsh[(idx >> 8) * XSTR + (idx & 255)] = __float2bfloat16(wv[idx]);
    }
    __syncthreads();

    for (int round = 0; round < 7; round++) {
        f32x16 c[2][4];
        #pragma unroll
        for (int mt = 0; mt < 2; mt++)
            #pragma unroll
            for (int j = 0; j < 4; j++)
                #pragma unroll
                for (int r = 0; r < 16; r++) c[mt][j][r] = 0.f;

        for (int kc = 0; kc < 16; kc++) {
            bf16x8 af[2], bfj[4];
            #pragma unroll
            for (int mt = 0; mt < 2; mt++)
                af[mt] = *(const bf16x8*)&Wsh[((2 * p + mt) * 32 + lo) * XSTR + kc * 16 + hi * 8];
            #pragma unroll
            for (int j = 0; j < 4; j++)
                bfj[j] = *(const bf16x8*)&Wsh[((4 * q + j) * 32 + lo) * XSTR + kc * 16 + hi * 8];
            #pragma unroll
            for (int mt = 0; mt < 2; mt++)
                #pragma unroll
                for (int j = 0; j < 4; j++)
                    c[mt][j] = __builtin_amdgcn_mfma_f32_32x32x16_bf16(af[mt], bfj[j], c[mt][j], 0, 0, 0);
        }

        float dsum = 0.f;
        #pragma unroll
        for (int mt = 0; mt < 2; mt++) {
            int Tm = 2 * p + mt;
            if ((Tm >> 2) == q) {
                int j = Tm - 4 * q;
                #pragma unroll
                for (int r = 0; r < 16; r++) {
                    int row = (r & 3) + 8 * (r >> 2) + 4 * hi;
                    if (row == lo) dsum += c[mt][j][r];
                }
            }
        }
        red[t] = dsum;
        __syncthreads();
        for (int s2 = 256; s2 > 0; s2 >>= 1) {
            if (t < s2) red[t] += red[t + s2];
            __syncthreads();
        }
        float invt = 1.0f / red[0];
        __syncthreads();

        #pragma unroll
        for (int mt = 0; mt < 2; mt++)
            #pragma unroll
            for (int j = 0; j < 4; j++)
                #pragma unroll
                for (int r = 0; r < 16; r++) {
                    int row = (2 * p + mt) * 32 + (r & 3) + 8 * (r >> 2) + 4 * hi;
                    int col = (4 * q + j) * 32 + lo;
                    Wsh[row * XSTR + col] = __float2bfloat16(c[mt][j][r] * invt);
                }
        __syncthreads();
    }

    if (t < 256) xv[t] = 1.0f + 0.01f * t;
    __syncthreads();
    for (int it = 0; it < 8; it++) {
        float y = 0.f;
        if (t < 256) {
            for (int ch = 0; ch < 32; ch++) {
                bf16x8 a = *(const bf16x8*)&Wsh[t * XSTR + ch * 8];
                #pragma unroll
                for (int e = 0; e < 8; e++) y += (float)a[e] * xv[ch * 8 + e];
            }
        }
        red[t] = (t < 256) ? y * y : 0.f;
        __syncthreads();
        for (int s2 = 256; s2 > 0; s2 >>= 1) {
            if (t < s2) red[t] += red[t + s2];
            __syncthreads();
        }
        if (t == 0) trsh = rsqrtf(red[0]);
        __syncthreads();
        if (t < 256) xv[t] = y * trsh;
        __syncthreads();
    }

    float z = 0.f;
    if (t < 256) {
        for (int i = 0; i < 256; i++) z += wv[i * 256 + t] * xv[i];
    }
    red[t] = (t < 256) ? z * z : 0.f;
    __syncthreads();
    for (int s2 = 256; s2 > 0; s2 >>= 1) {
        if (t < s2) red[t] += red[t + s2];
        __syncthreads();
    }
    if (t == 0) scal[2] = rsqrtf(red[0]);
}

// ---------------------------------------------------------------------------
// proj: fused MFMA projection (unchanged). Grid (64, 4), 512 thr.
// ---------------------------------------------------------------------------
__global__ __launch_bounds__(512, 2) void proj(const float* __restrict__ x,
                                               const float* __restrict__ wq,
                                               const float* __restrict__ wk,
                                               const float* __restrict__ wv,
                                               __hip_bfloat16* __restrict__ qT,
                                               __hip_bfloat16* __restrict__ kT,
                                               __hip_bfloat16* __restrict__ v) {
    __shared__ __align__(16) __hip_bfloat16 XT[64 * XSTR];
    __shared__ __align__(16) __hip_bfloat16 Tq[4][32 * 40];

    int t = threadIdx.x;
    int wave = t >> 6, lane = t & 63, lo = lane & 31, hi = lane >> 5;
    int n0 = blockIdx.x * 64;
    int b = blockIdx.y;
    const float* xb = x + ((size_t)b << 20);

    {
        int nl = t & 63, cg = t >> 6;
        #pragma unroll 8
        for (int i = 0; i < 32; i++) {
            int c = cg * 32 + i;
            XT[nl * XSTR + c] = __float2bfloat16(xb[(size_t)c * NPOS + n0 + nl]);
        }
    }
    __syncthreads();

    f32x16 accv[2], accq;
    #pragma unroll
    for (int it = 0; it < 2; it++)
        #pragma unroll
        for (int r = 0; r < 16; r++) accv[it][r] = 0.f;
    #pragma unroll
    for (int r = 0; r < 16; r++) accq[r] = 0.f;

    const float* wvrow = wv + (size_t)(wave * 32 + lo) * 256 + hi * 8;
    const float* wqkrow = ((wave < 2) ? wq : wk) + (size_t)lo * 256 + hi * 8;
    int qk_it = wave & 1;

    for (int kc = 0; kc < 16; kc++) {
        bf16x8 af0 = *(const bf16x8*)&XT[lo * XSTR + kc * 16 + hi * 8];
        bf16x8 af1 = *(const bf16x8*)&XT[(32 + lo) * XSTR + kc * 16 + hi * 8];
        float4 wa = *(const float4*)(wvrow + kc * 16);
        float4 wb = *(const float4*)(wvrow + kc * 16 + 4);
        bf16x8 bfv = cvt8(wa, wb);
        accv[0] = __builtin_amdgcn_mfma_f32_32x32x16_bf16(af0, bfv, accv[0], 0, 0, 0);
        accv[1] = __builtin_amdgcn_mfma_f32_32x32x16_bf16(af1, bfv, accv[1], 0, 0, 0);
        if (wave < 4) {
            float4 qa = *(const float4*)(wqkrow + kc * 16);
            float4 qb = *(const float4*)(wqkrow + kc * 16 + 4);
            bf16x8 bfq = cvt8(qa, qb);
            accq = __builtin_amdgcn_mfma_f32_32x32x16_bf16(qk_it ? af1 : af0, bfq, accq, 0, 0, 0);
        }
    }

    __hip_bfloat16* vbb = v + ((size_t)b << 20) + (size_t)(wave * 32 + lo) * NPOS + n0;
    #pragma unroll
    for (int it = 0; it < 2; it++)
        #pragma unroll
        for (int g = 0; g < 4; g++) {
            uint2 pk;
            pk.x = pk2(accv[it][4 * g + 0], accv[it][4 * g + 1]);
            pk.y = pk2(accv[it][4 * g + 2], accv[it][4 * g + 3]);
            *(uint2*)(vbb + it * 32 + 8 * g + 4 * hi) = pk;
        }

    if (wave < 4) {
        __hip_bfloat16* T = Tq[wave];
        #pragma unroll
        for (int r = 0; r < 16; r++) {
            int n = (r & 3) + 8 * (r >> 2) + 4 * hi;
            T[n * 40 + lo] = __float2bfloat16(accq[r]);
        }
    }
    __syncthreads();
    if (wave < 4) {
        __hip_bfloat16* T = Tq[wave];
        __hip_bfloat16* dst = ((wave < 2) ? qT : kT) + ((size_t)b << 17)
                              + (size_t)(n0 + qk_it * 32) * 32;
        #pragma unroll
        for (int p = 0; p < 2; p++) {
            int idx = p * 64 + lane;
            int n = idx >> 2, quad = idx & 3;
            bf16x8 row = *(const bf16x8*)&T[n * 40 + quad * 8];
            *(bf16x8*)(dst + (size_t)n * 32 + quad * 8) = row;
        }
    }
}

// ---------------------------------------------------------------------------
// attn_part: R2-proven loop, n-split. 256 thr (4 waves), grid 512
// (= 4 b x 64 m-tiles x 2 n-halves). Wave w: S^T quadrant (mtile=w>>1,
// ntile=w&1) over 64-n steps; PV e-range [64w, 64w+64), all 64 m.
// Emits unnormalized O (bf16) and L partials; no max-subtraction.
// ---------------------------------------------------------------------------
__global__ __launch_bounds__(256) void attn_part(const __hip_bfloat16* __restrict__ qT,
                                                 const __hip_bfloat16* __restrict__ kT,
                                                 const __hip_bfloat16* __restrict__ v,
                                                 const float* __restrict__ scal,
                                                 __hip_bfloat16* __restrict__ Opart,
                                                 float* __restrict__ Lsum) {
    __shared__ __hip_bfloat16 Plds[64 * 72];
    __shared__ float Lp[4][32];

    int t = threadIdx.x;
    int wave = t >> 6, lane = t & 63;
    int lo = lane & 31, hi = lane >> 5;

    // decode: x8 = b pair + m bit5; bit3 = n-half; high bits = m-tile rest
    int blk = blockIdx.x;
    int x8 = blk & 7;
    int b = x8 >> 1;
    int nh = (blk >> 3) & 1;
    int m0 = (((x8 & 1) << 5) + (blk >> 4)) << 6;
    int nbase = nh << 11;  // 0 or 2048

    const __hip_bfloat16* qTb = qT + ((size_t)b << 17);
    const __hip_bfloat16* kTb = kT + ((size_t)b << 17);
    const __hip_bfloat16* vb  = v  + ((size_t)b << 20);

    int mtile_s = wave >> 1, ntile_s = wave & 1;
    int e0w = wave << 6;
    float qkscale = scal[0] * scal[1] * 0.17677669529663687f;

    bf16x8 qf0 = *(const bf16x8*)(qTb + ((size_t)(m0 + mtile_s * 32 + lo)) * 32 + 0  + hi * 8);
    bf16x8 qf1 = *(const bf16x8*)(qTb + ((size_t)(m0 + mtile_s * 32 + lo)) * 32 + 16 + hi * 8);

    f32x16 acc[2][2];
    #pragma unroll
    for (int et = 0; et < 2; et++)
        #pragma unroll
        for (int mt = 0; mt < 2; mt++)
            #pragma unroll
            for (int r = 0; r < 16; r++) acc[et][mt][r] = 0.f;
    float l_acc = 0.f;

    const __hip_bfloat16* krow0 = kTb + (size_t)(ntile_s * 32 + lo) * 32 + hi * 8;
    const __hip_bfloat16* va0b = vb + (size_t)(e0w + lo) * NPOS + hi * 8;
    const __hip_bfloat16* va1b = vb + (size_t)(e0w + 32 + lo) * NPOS + hi * 8;

    for (int s = 0; s < 32; s++) {
        int n0 = nbase + 64 * s;
        // ---- S^T phase ----
        const __hip_bfloat16* krow = krow0 + (size_t)n0 * 32;
        bf16x8 kf0 = *(const bf16x8*)(krow);
        bf16x8 kf1 = *(const bf16x8*)(krow + 16);
        f32x16 sv;
        #pragma unroll
        for (int r = 0; r < 16; r++) sv[r] = 0.f;
        sv = __builtin_amdgcn_mfma_f32_32x32x16_bf16(kf0, qf0, sv, 0, 0, 0);
        sv = __builtin_amdgcn_mfma_f32_32x32x16_bf16(kf1, qf1, sv, 0, 0, 0);

        __syncthreads();  // previous PV reads of Plds are done
        int mrow = mtile_s * 32 + lo;
        #pragma unroll
        for (int g = 0; g < 4; g++) {
            float p0 = __expf(sv[4 * g + 0] * qkscale);
            float p1 = __expf(sv[4 * g + 1] * qkscale);
            float p2 = __expf(sv[4 * g + 2] * qkscale);
            float p3 = __expf(sv[4 * g + 3] * qkscale);
            l_acc += (p0 + p1) + (p2 + p3);
            uint2 pk;
            pk.x = pk2(p0, p1);
            pk.y = pk2(p2, p3);
            int nloc = ntile_s * 32 + 8 * g + 4 * hi;
            *(uint2*)(&Plds[mrow * 72 + nloc]) = pk;
        }
        __syncthreads();  // P tile ready

        // ---- PV phase (loads inline, R2 codegen) ----
        #pragma unroll
        for (int kc = 0; kc < 4; kc++) {
            bf16x8 pf0 = *(const bf16x8*)(&Plds[(lo)      * 72 + kc * 16 + hi * 8]);
            bf16x8 pf1 = *(const bf16x8*)(&Plds[(32 + lo) * 72 + kc * 16 + hi * 8]);
            bf16x8 vf0 = *(const bf16x8*)(va0b + n0 + kc * 16);
            bf16x8 vf1 = *(const bf16x8*)(va1b + n0 + kc * 16);
            acc[0][0] = __builtin_amdgcn_mfma_f32_32x32x16_bf16(vf0, pf0, acc[0][0], 0, 0, 0);
            acc[0][1] = __builtin_amdgcn_mfma_f32_32x32x16_bf16(vf0, pf1, acc[0][1], 0, 0, 0);
            acc[1][0] = __builtin_amdgcn_mfma_f32_32x32x16_bf16(vf1, pf0, acc[1][0], 0, 0, 0);
            acc[1][1] = __builtin_amdgcn_mfma_f32_32x32x16_bf16(vf1, pf1, acc[1][1], 0, 0, 0);
        }
    }

    // ---- L partials ----
    float lsum = l_acc + __shfl_xor(l_acc, 32, 64);
    if (lane < 32) Lp[wave][lane] = lsum;
    __syncthreads();
    if (wave == 0) {
        int l2 = lane & 31;
        float Lv = (lane < 32) ? (Lp[0][l2] + Lp[1][l2]) : (Lp[2][l2] + Lp[3][l2]);
        Lsum[(size_t)(nh * 4 + b) * NPOS + m0 + ((lane >> 5) << 5) + l2] = Lv;
    }

    // ---- store unnormalized O partial (bf16) ----
    __hip_bfloat16* Ob = Opart + ((size_t)(nh * 4 + b) << 20);
    #pragma unroll
    for (int mt = 0; mt < 2; mt++) {
        int m = m0 + mt * 32 + lo;
        #pragma unroll
        for (int et = 0; et < 2; et++) {
            #pragma unroll
            for (int r = 0; r < 16; r++) {
                int e = e0w + et * 32 + (r & 3) + 8 * (r >> 2) + 4 * hi;
                Ob[(size_t)e * NPOS + m] = __float2bfloat16(acc[et][mt][r]);
            }
        }
    }
}

// ---------------------------------------------------------------------------
// reduce_out: out = x + gamma*sig_v^-1 * (O0+O1)/(L0+L1). HBM-bound.
// grid (4, 256, 4) x 256 thr; thread = 4 consecutive m (float4/uint2).
// ---------------------------------------------------------------------------
__global__ __launch_bounds__(256) void reduce_out(const float* __restrict__ x,
                                                  const __hip_bfloat16* __restrict__ Opart,
                                                  const float* __restrict__ Lsum,
                                                  const float* __restrict__ scal,
                                                  const float* __restrict__ gam,
                                                  float* __restrict__ out) {
    int b = blockIdx.z, e = blockIdx.y;
    int m4 = (blockIdx.x * 256 + threadIdx.x) * 4;
    float gs = gam[0] * scal[2];

    size_t o = ((size_t)b << 20) + (size_t)e * NPOS + m4;
    float4 xv = *(const float4*)(x + o);
    const ushort* O0 = (const ushort*)(Opart + ((size_t)b << 20) + (size_t)e * NPOS + m4);
    const ushort* O1 = (const ushort*)(Opart + ((size_t)(4 + b) << 20) + (size_t)e * NPOS + m4);
    ushort4 a0 = *(const ushort4*)O0;
    ushort4 a1 = *(const ushort4*)O1;
    float4 L0 = *(const float4*)(Lsum + (size_t)b * NPOS + m4);
    float4 L1 = *(const float4*)(Lsum + (size_t)(4 + b) * NPOS + m4);

    float4 r;
    r.x = xv.x + gs * (b2f(a0.x) + b2f(a1.x)) / (L0.x + L1.x);
    r.y = xv.y + gs * (b2f(a0.y) + b2f(a1.y)) / (L0.y + L1.y);
    r.z = xv.z + gs * (b2f(a0.z) + b2f(a1.z)) / (L0.z + L1.z);
    r.w = xv.w + gs * (b2f(a0.w) + b2f(a1.w)) / (L0.w + L1.w);
    *(float4*)(out + o) = r;
}

// ---------------------------------------------------------------------------
extern "C" void kernel_launch(void* const* d_in, const int* in_sizes, int n_in,
                              void* d_out, int out_size, void* d_ws, size_t ws_size,
                              hipStream_t stream) {
    const float* x     = (const float*)d_in[0];
    const float* wq    = (const float*)d_in[1];
    const float* wk    = (const float*)d_in[2];
    const float* wv    = (const float*)d_in[3];
    const float* gamma = (const float*)d_in[4];
    float* out = (float*)d_out;

    char* wsb = (char*)d_ws;
    float* scal = (float*)wsb;                           // 256 B
    __hip_bfloat16* qT = (__hip_bfloat16*)(wsb + 256);   // 1 MB
    __hip_bfloat16* kT = qT + ((size_t)4 << 17);         // 1 MB
    __hip_bfloat16* vp = kT + ((size_t)4 << 17);         // 8 MB
    __hip_bfloat16* Opart = vp + ((size_t)4 << 20);      // 16 MB (2 halves x 4 b x 256e x 4096m)
    float* Lsum = (float*)(Opart + ((size_t)8 << 20));   // 128 KB

    proj<<<dim3(64, 4), 512, 0, stream>>>(x, wq, wk, wv, qT, kT, vp);
    sigma_all<<<3, 512, 0, stream>>>(wq, wk, wv, scal);
    attn_part<<<512, 256, 0, stream>>>(qT, kT, vp, scal, Opart, Lsum);
    reduce_out<<<dim3(4, 256, 4), 256, 0, stream>>>(x, Opart, Lsum, scal, gamma, out);
}

// Round 8
// 311.679 us; speedup vs baseline: 2.2819x; 1.0073x over previous
//
#include <hip/hip_runtime.h>
#include <hip/hip_bf16.h>
#include <math.h>

// ---------------------------------------------------------------------------
// SelfAttn2d: out = x + gamma * (V @ softmax(Q K^T / sqrt(32))^T)
// B=4, C=256, N=4096, D=32.
// Round 8: sigma_all rewrite. R7's sigma was 140us of near-idle latency
// (~150 barriers, t==0 serial loops, fp32 VALU chain). New: qk sigma as a
// single-wave MFMA squaring chain (af=bf trick), wv path keeps structure but
// all reductions are shuffle+1-barrier. proj/attn_part/reduce_out unchanged.
// ---------------------------------------------------------------------------

#define NPOS 4096
#define XSTR 264   // bf16 row stride for 256-col LDS matrices (33*16B)

typedef __bf16 bf16x8 __attribute__((ext_vector_type(8)));
typedef float  f32x16 __attribute__((ext_vector_type(16)));

static __device__ inline unsigned int pk2(float a, float b) {
    union { __hip_bfloat16 h[2]; unsigned int u; } x;
    x.h[0] = __float2bfloat16(a);
    x.h[1] = __float2bfloat16(b);
    return x.u;
}
static __device__ inline bf16x8 cvt8(float4 a, float4 b) {
    union { bf16x8 v; unsigned int u[4]; } t;
    t.u[0] = pk2(a.x, a.y); t.u[1] = pk2(a.z, a.w);
    t.u[2] = pk2(b.x, b.y); t.u[3] = pk2(b.z, b.w);
    return t.v;
}
static __device__ inline float b2f(unsigned short u) {
    union { float f; unsigned int i; } x;
    x.i = ((unsigned int)u) << 16;
    return x.f;
}

// ---------------------------------------------------------------------------
// sigma_all: block 0 -> sigma(wq), 1 -> sigma(wk), 2 -> sigma(wv). 512 thr.
// All sigmas: bf16 Gram^(2^k) squaring chain (trace-normalized) + power
// iterations + fp32 Rayleigh against the EXACT operator (lambda = ||w^T x||^2).
// ---------------------------------------------------------------------------
__global__ __launch_bounds__(512) void sigma_all(const float* __restrict__ wq,
                                                 const float* __restrict__ wk,
                                                 const float* __restrict__ wv,
                                                 float* __restrict__ scal) {
    __shared__ __align__(16) __hip_bfloat16 Wsh[256 * XSTR];  // 135 KB
    __shared__ float wred[8];
    __shared__ float xv[256];

    int t = threadIdx.x;
    int wave = t >> 6, lane = t & 63, lo = lane & 31, hi = lane >> 5;

    if (blockIdx.x < 2) {
        // ================= qk path: 32x256, single-wave MFMA chain ==========
        const float* w = (blockIdx.x == 0) ? wq : wk;
        __hip_bfloat16* Wb = Wsh;                    // [32][XSTR]
        __hip_bfloat16* As = Wsh + 32 * XSTR;        // [32][40] (80B rows: 5x16B odd)
        float* xs = (float*)(Wsh + 32 * XSTR + 32 * 40);  // [32] fp32, 4B-aligned

        if (t < 256) {
            for (int i = 0; i < 32; i++) {
                int idx = t + 256 * i;               // 0..8191
                Wb[(idx >> 8) * XSTR + (idx & 255)] = __float2bfloat16(w[idx]);
            }
        }
        __syncthreads();

        if (wave == 0) {
            // Gram G = W W^T via MFMA, A-frag == B-frag (row-major rows of W)
            f32x16 c;
            #pragma unroll
            for (int r = 0; r < 16; r++) c[r] = 0.f;
            for (int kc = 0; kc < 16; kc++) {
                bf16x8 af = *(const bf16x8*)&Wb[lo * XSTR + kc * 16 + hi * 8];
                c = __builtin_amdgcn_mfma_f32_32x32x16_bf16(af, af, c, 0, 0, 0);
            }
            // 8 squarings: trace-normalize -> As(bf16) -> c = As As^T
            for (int sq = 0; sq < 8; sq++) {
                float dsum = 0.f;
                #pragma unroll
                for (int r = 0; r < 16; r++) {
                    int row = (r & 3) + 8 * (r >> 2) + 4 * hi;
                    if (row == lo) dsum += c[r];
                }
                #pragma unroll
                for (int m = 1; m <= 32; m <<= 1) dsum += __shfl_xor(dsum, m, 64);
                float invt = 1.0f / dsum;
                #pragma unroll
                for (int r = 0; r < 16; r++) {
                    int row = (r & 3) + 8 * (r >> 2) + 4 * hi;
                    As[row * 40 + lo] = __float2bfloat16(c[r] * invt);
                }
                __builtin_amdgcn_s_waitcnt(0);  // LDS writes drained (single wave)
                bf16x8 a0 = *(const bf16x8*)&As[lo * 40 + hi * 8];
                bf16x8 a1 = *(const bf16x8*)&As[lo * 40 + 16 + hi * 8];
                #pragma unroll
                for (int r = 0; r < 16; r++) c[r] = 0.f;
                c = __builtin_amdgcn_mfma_f32_32x32x16_bf16(a0, a0, c, 0, 0, 0);
                c = __builtin_amdgcn_mfma_f32_32x32x16_bf16(a1, a1, c, 0, 0, 0);
            }
            // final normalize -> As (proportional to G^256)
            {
                float dsum = 0.f;
                #pragma unroll
                for (int r = 0; r < 16; r++) {
                    int row = (r & 3) + 8 * (r >> 2) + 4 * hi;
                    if (row == lo) dsum += c[r];
                }
                #pragma unroll
                for (int m = 1; m <= 32; m <<= 1) dsum += __shfl_xor(dsum, m, 64);
                float invt = 1.0f / dsum;
                #pragma unroll
                for (int r = 0; r < 16; r++) {
                    int row = (r & 3) + 8 * (r >> 2) + 4 * hi;
                    As[row * 40 + lo] = __float2bfloat16(c[r] * invt);
                }
                __builtin_amdgcn_s_waitcnt(0);
            }
            // 4 power iterations, x in registers (lane lo holds x[lo])
            float xr = 1.0f + 0.01f * lo;
            for (int it = 0; it < 4; it++) {
                float y = 0.f;
                #pragma unroll 8
                for (int j = 0; j < 32; j++) {
                    float xj = __shfl(xr, j, 64);
                    y += b2f(*(const unsigned short*)&As[lo * 40 + j]) * xj;
                }
                float ss = y * y;
                #pragma unroll
                for (int m = 1; m <= 16; m <<= 1) ss += __shfl_xor(ss, m, 64);
                xr = y * rsqrtf(ss);
            }
            if (hi == 0) xs[lo] = xr;
        }
        __syncthreads();

        // Rayleigh vs exact fp32: lambda = ||w^T x||^2 (x unit-norm)
        float z = 0.f;
        if (t < 256) {
            #pragma unroll 8
            for (int i = 0; i < 32; i++) z += w[i * 256 + t] * xs[i];
        }
        float zz = z * z;
        #pragma unroll
        for (int m = 1; m <= 32; m <<= 1) zz += __shfl_xor(zz, m, 64);
        if (lane == 0) wred[wave] = zz;
        __syncthreads();
        if (t == 0) {
            float lam = 0.f;
            for (int i = 0; i < 8; i++) lam += wred[i];
            scal[blockIdx.x] = rsqrtf(lam);
        }
        return;
    }

    // ================= wv path: 256x256 Gram^64 chain on MFMA ===============
    int p = wave >> 1;   // m-tile pair
    int q = wave & 1;    // j-quad

    for (int i = 0; i < 128; i++) {
        int idx = t + 512 * i;
        Wsh[(idx >> 8) * XSTR + (idx & 255)] = __float2bfloat16(wv[idx]);
    }
    __syncthreads();

    for (int round = 0; round < 7; round++) {
        f32x16 c[2][4];
        #pragma unroll
        for (int mt = 0; mt < 2; mt++)
            #pragma unroll
            for (int j = 0; j < 4; j++)
                #pragma unroll
                for (int r = 0; r < 16; r++) c[mt][j][r] = 0.f;

        for (int kc = 0; kc < 16; kc++) {
            bf16x8 af[2], bfj[4];
            #pragma unroll
            for (int mt = 0; mt < 2; mt++)
                af[mt] = *(const bf16x8*)&Wsh[((2 * p + mt) * 32 + lo) * XSTR + kc * 16 + hi * 8];
            #pragma unroll
            for (int j = 0; j < 4; j++)
                bfj[j] = *(const bf16x8*)&Wsh[((4 * q + j) * 32 + lo) * XSTR + kc * 16 + hi * 8];
            #pragma unroll
            for (int mt = 0; mt < 2; mt++)
                #pragma unroll
                for (int j = 0; j < 4; j++)
                    c[mt][j] = __builtin_amdgcn_mfma_f32_32x32x16_bf16(af[mt], bfj[j], c[mt][j], 0, 0, 0);
        }

        // trace via shuffle + one barrier
        float dsum = 0.f;
        #pragma unroll
        for (int mt = 0; mt < 2; mt++) {
            int Tm = 2 * p + mt;
            if ((Tm >> 2) == q) {
                int j = Tm - 4 * q;
                #pragma unroll
                for (int r = 0; r < 16; r++) {
                    int row = (r & 3) + 8 * (r >> 2) + 4 * hi;
                    if (row == lo) dsum += c[mt][j][r];
                }
            }
        }
        #pragma unroll
        for (int m = 1; m <= 32; m <<= 1) dsum += __shfl_xor(dsum, m, 64);
        if (lane == 0) wred[wave] = dsum;
        __syncthreads();   // Wsh reads done + wred visible
        float tr = 0.f;
        for (int i = 0; i < 8; i++) tr += wred[i];
        float invt = 1.0f / tr;

        #pragma unroll
        for (int mt = 0; mt < 2; mt++)
            #pragma unroll
            for (int j = 0; j < 4; j++)
                #pragma unroll
                for (int r = 0; r < 16; r++) {
                    int row = (2 * p + mt) * 32 + (r & 3) + 8 * (r >> 2) + 4 * hi;
                    int col = (4 * q + j) * 32 + lo;
                    Wsh[row * XSTR + col] = __float2bfloat16(c[mt][j][r] * invt);
                }
        __syncthreads();
    }

    // 8 power iterations on A = Wsh (bf16), shuffle reductions
    if (t < 256) xv[t] = 1.0f + 0.01f * t;
    __syncthreads();
    for (int it = 0; it < 8; it++) {
        float y = 0.f;
        if (t < 256) {
            for (int ch = 0; ch < 32; ch++) {
                bf16x8 a = *(const bf16x8*)&Wsh[t * XSTR + ch * 8];
                #pragma unroll
                for (int e = 0; e < 8; e++) y += (float)a[e] * xv[ch * 8 + e];
            }
        }
        float ss = y * y;
        #pragma unroll
        for (int m = 1; m <= 32; m <<= 1) ss += __shfl_xor(ss, m, 64);
        if (lane == 0) wred[wave] = ss;
        __syncthreads();
        float s8 = 0.f;
        for (int i = 0; i < 8; i++) s8 += wred[i];
        float nrm = rsqrtf(s8);
        if (t < 256) xv[t] = y * nrm;
        __syncthreads();
    }

    // Rayleigh in fp32 vs exact G: lambda = ||wv^T x||^2
    float z = 0.f;
    if (t < 256) {
        for (int i = 0; i < 256; i++) z += wv[i * 256 + t] * xv[i];
    }
    float zz = z * z;
    #pragma unroll
    for (int m = 1; m <= 32; m <<= 1) zz += __shfl_xor(zz, m, 64);
    if (lane == 0) wred[wave] = zz;
    __syncthreads();
    if (t == 0) {
        float lam = 0.f;
        for (int i = 0; i < 8; i++) lam += wred[i];
        scal[2] = rsqrtf(lam);
    }
}

// ---------------------------------------------------------------------------
// proj: fused MFMA projection (unchanged from R7). Grid (64, 4), 512 thr.
// ---------------------------------------------------------------------------
__global__ __launch_bounds__(512, 2) void proj(const float* __restrict__ x,
                                               const float* __restrict__ wq,
                                               const float* __restrict__ wk,
                                               const float* __restrict__ wv,
                                               __hip_bfloat16* __restrict__ qT,
                                               __hip_bfloat16* __restrict__ kT,
                                               __hip_bfloat16* __restrict__ v) {
    __shared__ __align__(16) __hip_bfloat16 XT[64 * XSTR];
    __shared__ __align__(16) __hip_bfloat16 Tq[4][32 * 40];

    int t = threadIdx.x;
    int wave = t >> 6, lane = t & 63, lo = lane & 31, hi = lane >> 5;
    int n0 = blockIdx.x * 64;
    int b = blockIdx.y;
    const float* xb = x + ((size_t)b << 20);

    {
        int nl = t & 63, cg = t >> 6;
        #pragma unroll 8
        for (int i = 0; i < 32; i++) {
            int c = cg * 32 + i;
            XT[nl * XSTR + c] = __float2bfloat16(xb[(size_t)c * NPOS + n0 + nl]);
        }
    }
    __syncthreads();

    f32x16 accv[2], accq;
    #pragma unroll
    for (int it = 0; it < 2; it++)
        #pragma unroll
        for (int r = 0; r < 16; r++) accv[it][r] = 0.f;
    #pragma unroll
    for (int r = 0; r < 16; r++) accq[r] = 0.f;

    const float* wvrow = wv + (size_t)(wave * 32 + lo) * 256 + hi * 8;
    const float* wqkrow = ((wave < 2) ? wq : wk) + (size_t)lo * 256 + hi * 8;
    int qk_it = wave & 1;

    for (int kc = 0; kc < 16; kc++) {
        bf16x8 af0 = *(const bf16x8*)&XT[lo * XSTR + kc * 16 + hi * 8];
        bf16x8 af1 = *(const bf16x8*)&XT[(32 + lo) * XSTR + kc * 16 + hi * 8];
        float4 wa = *(const float4*)(wvrow + kc * 16);
        float4 wb = *(const float4*)(wvrow + kc * 16 + 4);
        bf16x8 bfv = cvt8(wa, wb);
        accv[0] = __builtin_amdgcn_mfma_f32_32x32x16_bf16(af0, bfv, accv[0], 0, 0, 0);
        accv[1] = __builtin_amdgcn_mfma_f32_32x32x16_bf16(af1, bfv, accv[1], 0, 0, 0);
        if (wave < 4) {
            float4 qa = *(const float4*)(wqkrow + kc * 16);
            float4 qb = *(const float4*)(wqkrow + kc * 16 + 4);
            bf16x8 bfq = cvt8(qa, qb);
            accq = __builtin_amdgcn_mfma_f32_32x32x16_bf16(qk_it ? af1 : af0, bfq, accq, 0, 0, 0);
        }
    }

    __hip_bfloat16* vbb = v + ((size_t)b << 20) + (size_t)(wave * 32 + lo) * NPOS + n0;
    #pragma unroll
    for (int it = 0; it < 2; it++)
        #pragma unroll
        for (int g = 0; g < 4; g++) {
            uint2 pk;
            pk.x = pk2(accv[it][4 * g + 0], accv[it][4 * g + 1]);
            pk.y = pk2(accv[it][4 * g + 2], accv[it][4 * g + 3]);
            *(uint2*)(vbb + it * 32 + 8 * g + 4 * hi) = pk;
        }

    if (wave < 4) {
        __hip_bfloat16* T = Tq[wave];
        #pragma unroll
        for (int r = 0; r < 16; r++) {
            int n = (r & 3) + 8 * (r >> 2) + 4 * hi;
            T[n * 40 + lo] = __float2bfloat16(accq[r]);
        }
    }
    __syncthreads();
    if (wave < 4) {
        __hip_bfloat16* T = Tq[wave];
        __hip_bfloat16* dst = ((wave < 2) ? qT : kT) + ((size_t)b << 17)
                              + (size_t)(n0 + qk_it * 32) * 32;
        #pragma unroll
        for (int p = 0; p < 2; p++) {
            int idx = p * 64 + lane;
            int n = idx >> 2, quad = idx & 3;
            bf16x8 row = *(const bf16x8*)&T[n * 40 + quad * 8];
            *(bf16x8*)(dst + (size_t)n * 32 + quad * 8) = row;
        }
    }
}

// ---------------------------------------------------------------------------
// attn_part: R2-proven loop, n-split (unchanged from R7). 256 thr, grid 512.
// ---------------------------------------------------------------------------
__global__ __launch_bounds__(256) void attn_part(const __hip_bfloat16* __restrict__ qT,
                                                 const __hip_bfloat16* __restrict__ kT,
                                                 const __hip_bfloat16* __restrict__ v,
                                                 const float* __restrict__ scal,
                                                 __hip_bfloat16* __restrict__ Opart,
                                                 float* __restrict__ Lsum) {
    __shared__ __hip_bfloat16 Plds[64 * 72];
    __shared__ float Lp[4][32];

    int t = threadIdx.x;
    int wave = t >> 6, lane = t & 63;
    int lo = lane & 31, hi = lane >> 5;

    int blk = blockIdx.x;
    int x8 = blk & 7;
    int b = x8 >> 1;
    int nh = (blk >> 3) & 1;
    int m0 = (((x8 & 1) << 5) + (blk >> 4)) << 6;
    int nbase = nh << 11;

    const __hip_bfloat16* qTb = qT + ((size_t)b << 17);
    const __hip_bfloat16* kTb = kT + ((size_t)b << 17);
    const __hip_bfloat16* vb  = v  + ((size_t)b << 20);

    int mtile_s = wave >> 1, ntile_s = wave & 1;
    int e0w = wave << 6;
    float qkscale = scal[0] * scal[1] * 0.17677669529663687f;

    bf16x8 qf0 = *(const bf16x8*)(qTb + ((size_t)(m0 + mtile_s * 32 + lo)) * 32 + 0  + hi * 8);
    bf16x8 qf1 = *(const bf16x8*)(qTb + ((size_t)(m0 + mtile_s * 32 + lo)) * 32 + 16 + hi * 8);

    f32x16 acc[2][2];
    #pragma unroll
    for (int et = 0; et < 2; et++)
        #pragma unroll
        for (int mt = 0; mt < 2; mt++)
            #pragma unroll
            for (int r = 0; r < 16; r++) acc[et][mt][r] = 0.f;
    float l_acc = 0.f;

    const __hip_bfloat16* krow0 = kTb + (size_t)(ntile_s * 32 + lo) * 32 + hi * 8;
    const __hip_bfloat16* va0b = vb + (size_t)(e0w + lo) * NPOS + hi * 8;
    const __hip_bfloat16* va1b = vb + (size_t)(e0w + 32 + lo) * NPOS + hi * 8;

    for (int s = 0; s < 32; s++) {
        int n0 = nbase + 64 * s;
        const __hip_bfloat16* krow = krow0 + (size_t)n0 * 32;
        bf16x8 kf0 = *(const bf16x8*)(krow);
        bf16x8 kf1 = *(const bf16x8*)(krow + 16);
        f32x16 sv;
        #pragma unroll
        for (int r = 0; r < 16; r++) sv[r] = 0.f;
        sv = __builtin_amdgcn_mfma_f32_32x32x16_bf16(kf0, qf0, sv, 0, 0, 0);
        sv = __builtin_amdgcn_mfma_f32_32x32x16_bf16(kf1, qf1, sv, 0, 0, 0);

        __syncthreads();
        int mrow = mtile_s * 32 + lo;
        #pragma unroll
        for (int g = 0; g < 4; g++) {
            float p0 = __expf(sv[4 * g + 0] * qkscale);
            float p1 = __expf(sv[4 * g + 1] * qkscale);
            float p2 = __expf(sv[4 * g + 2] * qkscale);
            float p3 = __expf(sv[4 * g + 3] * qkscale);
            l_acc += (p0 + p1) + (p2 + p3);
            uint2 pk;
            pk.x = pk2(p0, p1);
            pk.y = pk2(p2, p3);
            int nloc = ntile_s * 32 + 8 * g + 4 * hi;
            *(uint2*)(&Plds[mrow * 72 + nloc]) = pk;
        }
        __syncthreads();

        #pragma unroll
        for (int kc = 0; kc < 4; kc++) {
            bf16x8 pf0 = *(const bf16x8*)(&Plds[(lo)      * 72 + kc * 16 + hi * 8]);
            bf16x8 pf1 = *(const bf16x8*)(&Plds[(32 + lo) * 72 + kc * 16 + hi * 8]);
            bf16x8 vf0 = *(const bf16x8*)(va0b + n0 + kc * 16);
            bf16x8 vf1 = *(const bf16x8*)(va1b + n0 + kc * 16);
            acc[0][0] = __builtin_amdgcn_mfma_f32_32x32x16_bf16(vf0, pf0, acc[0][0], 0, 0, 0);
            acc[0][1] = __builtin_amdgcn_mfma_f32_32x32x16_bf16(vf0, pf1, acc[0][1], 0, 0, 0);
            acc[1][0] = __builtin_amdgcn_mfma_f32_32x32x16_bf16(vf1, pf0, acc[1][0], 0, 0, 0);
            acc[1][1] = __builtin_amdgcn_mfma_f32_32x32x16_bf16(vf1, pf1, acc[1][1], 0, 0, 0);
        }
    }

    float lsum = l_acc + __shfl_xor(l_acc, 32, 64);
    if (lane < 32) Lp[wave][lane] = lsum;
    __syncthreads();
    if (wave == 0) {
        int l2 = lane & 31;
        float Lv = (lane < 32) ? (Lp[0][l2] + Lp[1][l2]) : (Lp[2][l2] + Lp[3][l2]);
        Lsum[(size_t)(nh * 4 + b) * NPOS + m0 + ((lane >> 5) << 5) + l2] = Lv;
    }

    __hip_bfloat16* Ob = Opart + ((size_t)(nh * 4 + b) << 20);
    #pragma unroll
    for (int mt = 0; mt < 2; mt++) {
        int m = m0 + mt * 32 + lo;
        #pragma unroll
        for (int et = 0; et < 2; et++) {
            #pragma unroll
            for (int r = 0; r < 16; r++) {
                int e = e0w + et * 32 + (r & 3) + 8 * (r >> 2) + 4 * hi;
                Ob[(size_t)e * NPOS + m] = __float2bfloat16(acc[et][mt][r]);
            }
        }
    }
}

// ---------------------------------------------------------------------------
// reduce_out: out = x + gamma*sig_v^-1 * (O0+O1)/(L0+L1) (unchanged).
// ---------------------------------------------------------------------------
__global__ __launch_bounds__(256) void reduce_out(const float* __restrict__ x,
                                                  const __hip_bfloat16* __restrict__ Opart,
                                                  const float* __restrict__ Lsum,
                                                  const float* __restrict__ scal,
                                                  const float* __restrict__ gam,
                                                  float* __restrict__ out) {
    int b = blockIdx.z, e = blockIdx.y;
    int m4 = (blockIdx.x * 256 + threadIdx.x) * 4;
    float gs = gam[0] * scal[2];

    size_t o = ((size_t)b << 20) + (size_t)e * NPOS + m4;
    float4 xv = *(const float4*)(x + o);
    const ushort* O0 = (const ushort*)(Opart + ((size_t)b << 20) + (size_t)e * NPOS + m4);
    const ushort* O1 = (const ushort*)(Opart + ((size_t)(4 + b) << 20) + (size_t)e * NPOS + m4);
    ushort4 a0 = *(const ushort4*)O0;
    ushort4 a1 = *(const ushort4*)O1;
    float4 L0 = *(const float4*)(Lsum + (size_t)b * NPOS + m4);
    float4 L1 = *(const float4*)(Lsum + (size_t)(4 + b) * NPOS + m4);

    float4 r;
    r.x = xv.x + gs * (b2f(a0.x) + b2f(a1.x)) / (L0.x + L1.x);
    r.y = xv.y + gs * (b2f(a0.y) + b2f(a1.y)) / (L0.y + L1.y);
    r.z = xv.z + gs * (b2f(a0.z) + b2f(a1.z)) / (L0.z + L1.z);
    r.w = xv.w + gs * (b2f(a0.w) + b2f(a1.w)) / (L0.w + L1.w);
    *(float4*)(out + o) = r;
}

// ---------------------------------------------------------------------------
extern "C" void kernel_launch(void* const* d_in, const int* in_sizes, int n_in,
                              void* d_out, int out_size, void* d_ws, size_t ws_size,
                              hipStream_t stream) {
    const float* x     = (const float*)d_in[0];
    const float* wq    = (const float*)d_in[1];
    const float* wk    = (const float*)d_in[2];
    const float* wv    = (const float*)d_in[3];
    const float* gamma = (const float*)d_in[4];
    float* out = (float*)d_out;

    char* wsb = (char*)d_ws;
    float* scal = (float*)wsb;                           // 256 B
    __hip_bfloat16* qT = (__hip_bfloat16*)(wsb + 256);   // 1 MB
    __hip_bfloat16* kT = qT + ((size_t)4 << 17);         // 1 MB
    __hip_bfloat16* vp = kT + ((size_t)4 << 17);         // 8 MB
    __hip_bfloat16* Opart = vp + ((size_t)4 << 20);      // 16 MB
    float* Lsum = (float*)(Opart + ((size_t)8 << 20));   // 128 KB

    sigma_all<<<3, 512, 0, stream>>>(wq, wk, wv, scal);
    proj<<<dim3(64, 4), 512, 0, stream>>>(x, wq, wk, wv, qT, kT, vp);
    attn_part<<<512, 256, 0, stream>>>(qT, kT, vp, scal, Opart, Lsum);
    reduce_out<<<dim3(4, 256, 4), 256, 0, stream>>>(x, Opart, Lsum, scal, gamma, out);
}

// Round 9
// 292.794 us; speedup vs baseline: 2.4291x; 1.0645x over previous
//
#include <hip/hip_runtime.h>
#include <hip/hip_bf16.h>
#include <math.h>

// ---------------------------------------------------------------------------
// SelfAttn2d: out = x + gamma * (V @ softmax(Q K^T / sqrt(32))^T)
// B=4, C=256, N=4096, D=32.
// Round 9: fuse sigma into proj (sigma has no dependency on proj's outputs;
// proj doesn't read scal). Grid (65,4): x==64 -> sigma blocks y=0,1,2.
// R7/R8 showed sigma's 135us is idle-device latency, not compute: two very
// different implementations timed identically with all counters ~0.05%.
// Running it concurrently with proj's 256 blocks makes it (nearly) free.
// ---------------------------------------------------------------------------

#define NPOS 4096
#define XSTR 264   // bf16 row stride for 256-col LDS matrices (33*16B)

typedef __bf16 bf16x8 __attribute__((ext_vector_type(8)));
typedef float  f32x16 __attribute__((ext_vector_type(16)));

static __device__ inline unsigned int pk2(float a, float b) {
    union { __hip_bfloat16 h[2]; unsigned int u; } x;
    x.h[0] = __float2bfloat16(a);
    x.h[1] = __float2bfloat16(b);
    return x.u;
}
static __device__ inline bf16x8 cvt8(float4 a, float4 b) {
    union { bf16x8 v; unsigned int u[4]; } t;
    t.u[0] = pk2(a.x, a.y); t.u[1] = pk2(a.z, a.w);
    t.u[2] = pk2(b.x, b.y); t.u[3] = pk2(b.z, b.w);
    return t.v;
}
static __device__ inline float b2f(unsigned short u) {
    union { float f; unsigned int i; } x;
    x.i = ((unsigned int)u) << 16;
    return x.f;
}

// ---------------------------------------------------------------------------
// proj_sigma: grid (65, 4), 512 thr.
//   blockIdx.x < 64 : proj path (fused MFMA projection, unchanged logic)
//   blockIdx.x == 64: sigma path, y=0 -> sigma(wq), 1 -> sigma(wk),
//                     2 -> sigma(wv), 3 -> exit.
// ---------------------------------------------------------------------------
__global__ __launch_bounds__(512) void proj_sigma(const float* __restrict__ x,
                                                  const float* __restrict__ wq,
                                                  const float* __restrict__ wk,
                                                  const float* __restrict__ wv,
                                                  __hip_bfloat16* __restrict__ qT,
                                                  __hip_bfloat16* __restrict__ kT,
                                                  __hip_bfloat16* __restrict__ v,
                                                  float* __restrict__ scal) {
    __shared__ __align__(16) __hip_bfloat16 Wsh[256 * XSTR];  // 135 KB (sigma) / overlay (proj)
    __shared__ float wred[8];
    __shared__ float xv[256];

    int t = threadIdx.x;
    int wave = t >> 6, lane = t & 63, lo = lane & 31, hi = lane >> 5;

    if (blockIdx.x == 64) {
        // ===================== sigma path =====================
        int sb = blockIdx.y;
        if (sb == 3) return;

        if (sb < 2) {
            // ---- qk: 32x256, single-wave MFMA squaring chain ----
            const float* w = (sb == 0) ? wq : wk;
            __hip_bfloat16* Wb = Wsh;                    // [32][XSTR]
            __hip_bfloat16* As = Wsh + 32 * XSTR;        // [32][40]
            float* xs = (float*)(Wsh + 32 * XSTR + 32 * 40);  // [32] fp32

            if (t < 256) {
                for (int i = 0; i < 32; i++) {
                    int idx = t + 256 * i;
                    Wb[(idx >> 8) * XSTR + (idx & 255)] = __float2bfloat16(w[idx]);
                }
            }
            __syncthreads();

            if (wave == 0) {
                f32x16 c;
                #pragma unroll
                for (int r = 0; r < 16; r++) c[r] = 0.f;
                for (int kc = 0; kc < 16; kc++) {
                    bf16x8 af = *(const bf16x8*)&Wb[lo * XSTR + kc * 16 + hi * 8];
                    c = __builtin_amdgcn_mfma_f32_32x32x16_bf16(af, af, c, 0, 0, 0);
                }
                for (int sq = 0; sq < 8; sq++) {
                    float dsum = 0.f;
                    #pragma unroll
                    for (int r = 0; r < 16; r++) {
                        int row = (r & 3) + 8 * (r >> 2) + 4 * hi;
                        if (row == lo) dsum += c[r];
                    }
                    #pragma unroll
                    for (int m = 1; m <= 32; m <<= 1) dsum += __shfl_xor(dsum, m, 64);
                    float invt = 1.0f / dsum;
                    #pragma unroll
                    for (int r = 0; r < 16; r++) {
                        int row = (r & 3) + 8 * (r >> 2) + 4 * hi;
                        As[row * 40 + lo] = __float2bfloat16(c[r] * invt);
                    }
                    __builtin_amdgcn_s_waitcnt(0);
                    bf16x8 a0 = *(const bf16x8*)&As[lo * 40 + hi * 8];
                    bf16x8 a1 = *(const bf16x8*)&As[lo * 40 + 16 + hi * 8];
                    #pragma unroll
                    for (int r = 0; r < 16; r++) c[r] = 0.f;
                    c = __builtin_amdgcn_mfma_f32_32x32x16_bf16(a0, a0, c, 0, 0, 0);
                    c = __builtin_amdgcn_mfma_f32_32x32x16_bf16(a1, a1, c, 0, 0, 0);
                }
                {
                    float dsum = 0.f;
                    #pragma unroll
                    for (int r = 0; r < 16; r++) {
                        int row = (r & 3) + 8 * (r >> 2) + 4 * hi;
                        if (row == lo) dsum += c[r];
                    }
                    #pragma unroll
                    for (int m = 1; m <= 32; m <<= 1) dsum += __shfl_xor(dsum, m, 64);
                    float invt = 1.0f / dsum;
                    #pragma unroll
                    for (int r = 0; r < 16; r++) {
                        int row = (r & 3) + 8 * (r >> 2) + 4 * hi;
                        As[row * 40 + lo] = __float2bfloat16(c[r] * invt);
                    }
                    __builtin_amdgcn_s_waitcnt(0);
                }
                float xr = 1.0f + 0.01f * lo;
                for (int it = 0; it < 4; it++) {
                    float y = 0.f;
                    #pragma unroll 8
                    for (int j = 0; j < 32; j++) {
                        float xj = __shfl(xr, j, 64);
                        y += b2f(*(const unsigned short*)&As[lo * 40 + j]) * xj;
                    }
                    float ss = y * y;
                    #pragma unroll
                    for (int m = 1; m <= 16; m <<= 1) ss += __shfl_xor(ss, m, 64);
                    xr = y * rsqrtf(ss);
                }
                if (hi == 0) xs[lo] = xr;
            }
            __syncthreads();

            float z = 0.f;
            if (t < 256) {
                #pragma unroll 8
                for (int i = 0; i < 32; i++) z += w[i * 256 + t] * xs[i];
            }
            float zz = z * z;
            #pragma unroll
            for (int m = 1; m <= 32; m <<= 1) zz += __shfl_xor(zz, m, 64);
            if (lane == 0) wred[wave] = zz;
            __syncthreads();
            if (t == 0) {
                float lam = 0.f;
                for (int i = 0; i < 8; i++) lam += wred[i];
                scal[sb] = rsqrtf(lam);
            }
            return;
        }

        // ---- wv: 256x256 Gram^64 chain on MFMA ----
        int p = wave >> 1;
        int q = wave & 1;

        for (int i = 0; i < 128; i++) {
            int idx = t + 512 * i;
            Wsh[(idx >> 8) * XSTR + (idx & 255)] = __float2bfloat16(wv[idx]);
        }
        __syncthreads();

        for (int round = 0; round < 7; round++) {
            f32x16 c[2][4];
            #pragma unroll
            for (int mt = 0; mt < 2; mt++)
                #pragma unroll
                for (int j = 0; j < 4; j++)
                    #pragma unroll
                    for (int r = 0; r < 16; r++) c[mt][j][r] = 0.f;

            for (int kc = 0; kc < 16; kc++) {
                bf16x8 af[2], bfj[4];
                #pragma unroll
                for (int mt = 0; mt < 2; mt++)
                    af[mt] = *(const bf16x8*)&Wsh[((2 * p + mt) * 32 + lo) * XSTR + kc * 16 + hi * 8];
                #pragma unroll
                for (int j = 0; j < 4; j++)
                    bfj[j] = *(const bf16x8*)&Wsh[((4 * q + j) * 32 + lo) * XSTR + kc * 16 + hi * 8];
                #pragma unroll
                for (int mt = 0; mt < 2; mt++)
                    #pragma unroll
                    for (int j = 0; j < 4; j++)
                        c[mt][j] = __builtin_amdgcn_mfma_f32_32x32x16_bf16(af[mt], bfj[j], c[mt][j], 0, 0, 0);
            }

            float dsum = 0.f;
            #pragma unroll
            for (int mt = 0; mt < 2; mt++) {
                int Tm = 2 * p + mt;
                if ((Tm >> 2) == q) {
                    int j = Tm - 4 * q;
                    #pragma unroll
                    for (int r = 0; r < 16; r++) {
                        int row = (r & 3) + 8 * (r >> 2) + 4 * hi;
                        if (row == lo) dsum += c[mt][j][r];
                    }
                }
            }
            #pragma unroll
            for (int m = 1; m <= 32; m <<= 1) dsum += __shfl_xor(dsum, m, 64);
            if (lane == 0) wred[wave] = dsum;
            __syncthreads();
            float tr = 0.f;
            for (int i = 0; i < 8; i++) tr += wred[i];
            float invt = 1.0f / tr;

            #pragma unroll
            for (int mt = 0; mt < 2; mt++)
                #pragma unroll
                for (int j = 0; j < 4; j++)
                    #pragma unroll
                    for (int r = 0; r < 16; r++) {
                        int row = (2 * p + mt) * 32 + (r & 3) + 8 * (r >> 2) + 4 * hi;
                        int col = (4 * q + j) * 32 + lo;
                        Wsh[row * XSTR + col] = __float2bfloat16(c[mt][j][r] * invt);
                    }
            __syncthreads();
        }

        if (t < 256) xv[t] = 1.0f + 0.01f * t;
        __syncthreads();
        for (int it = 0; it < 8; it++) {
            float y = 0.f;
            if (t < 256) {
                for (int ch = 0; ch < 32; ch++) {
                    bf16x8 a = *(const bf16x8*)&Wsh[t * XSTR + ch * 8];
                    #pragma unroll
                    for (int e = 0; e < 8; e++) y += (float)a[e] * xv[ch * 8 + e];
                }
            }
            float ss = y * y;
            #pragma unroll
            for (int m = 1; m <= 32; m <<= 1) ss += __shfl_xor(ss, m, 64);
            if (lane == 0) wred[wave] = ss;
            __syncthreads();
            float s8 = 0.f;
            for (int i = 0; i < 8; i++) s8 += wred[i];
            float nrm = rsqrtf(s8);
            if (t < 256) xv[t] = y * nrm;
            __syncthreads();
        }

        float z = 0.f;
        if (t < 256) {
            for (int i = 0; i < 256; i++) z += wv[i * 256 + t] * xv[i];
        }
        float zz = z * z;
        #pragma unroll
        for (int m = 1; m <= 32; m <<= 1) zz += __shfl_xor(zz, m, 64);
        if (lane == 0) wred[wave] = zz;
        __syncthreads();
        if (t == 0) {
            float lam = 0.f;
            for (int i = 0; i < 8; i++) lam += wred[i];
            scal[2] = rsqrtf(lam);
        }
        return;
    }

    // ===================== proj path (unchanged logic) =====================
    __hip_bfloat16* XT  = Wsh;                 // [64][XSTR] = 33.8 KB
    __hip_bfloat16* TqB = Wsh + 64 * XSTR;     // 4 x [32*40] = 10 KB

    int n0 = blockIdx.x * 64;
    int b = blockIdx.y;
    const float* xb = x + ((size_t)b << 20);

    {
        int nl = t & 63, cg = t >> 6;
        #pragma unroll 8
        for (int i = 0; i < 32; i++) {
            int c = cg * 32 + i;
            XT[nl * XSTR + c] = __float2bfloat16(xb[(size_t)c * NPOS + n0 + nl]);
        }
    }
    __syncthreads();

    f32x16 accv[2], accq;
    #pragma unroll
    for (int it = 0; it < 2; it++)
        #pragma unroll
        for (int r = 0; r < 16; r++) accv[it][r] = 0.f;
    #pragma unroll
    for (int r = 0; r < 16; r++) accq[r] = 0.f;

    const float* wvrow = wv + (size_t)(wave * 32 + lo) * 256 + hi * 8;
    const float* wqkrow = ((wave < 2) ? wq : wk) + (size_t)lo * 256 + hi * 8;
    int qk_it = wave & 1;

    for (int kc = 0; kc < 16; kc++) {
        bf16x8 af0 = *(const bf16x8*)&XT[lo * XSTR + kc * 16 + hi * 8];
        bf16x8 af1 = *(const bf16x8*)&XT[(32 + lo) * XSTR + kc * 16 + hi * 8];
        float4 wa = *(const float4*)(wvrow + kc * 16);
        float4 wb = *(const float4*)(wvrow + kc * 16 + 4);
        bf16x8 bfv = cvt8(wa, wb);
        accv[0] = __builtin_amdgcn_mfma_f32_32x32x16_bf16(af0, bfv, accv[0], 0, 0, 0);
        accv[1] = __builtin_amdgcn_mfma_f32_32x32x16_bf16(af1, bfv, accv[1], 0, 0, 0);
        if (wave < 4) {
            float4 qa = *(const float4*)(wqkrow + kc * 16);
            float4 qb = *(const float4*)(wqkrow + kc * 16 + 4);
            bf16x8 bfq = cvt8(qa, qb);
            accq = __builtin_amdgcn_mfma_f32_32x32x16_bf16(qk_it ? af1 : af0, bfq, accq, 0, 0, 0);
        }
    }

    __hip_bfloat16* vbb = v + ((size_t)b << 20) + (size_t)(wave * 32 + lo) * NPOS + n0;
    #pragma unroll
    for (int it = 0; it < 2; it++)
        #pragma unroll
        for (int g = 0; g < 4; g++) {
            uint2 pk;
            pk.x = pk2(accv[it][4 * g + 0], accv[it][4 * g + 1]);
            pk.y = pk2(accv[it][4 * g + 2], accv[it][4 * g + 3]);
            *(uint2*)(vbb + it * 32 + 8 * g + 4 * hi) = pk;
        }

    if (wave < 4) {
        __hip_bfloat16* T = TqB + wave * (32 * 40);
        #pragma unroll
        for (int r = 0; r < 16; r++) {
            int n = (r & 3) + 8 * (r >> 2) + 4 * hi;
            T[n * 40 + lo] = __float2bfloat16(accq[r]);
        }
    }
    __syncthreads();
    if (wave < 4) {
        __hip_bfloat16* T = TqB + wave * (32 * 40);
        __hip_bfloat16* dst = ((wave < 2) ? qT : kT) + ((size_t)b << 17)
                              + (size_t)(n0 + qk_it * 32) * 32;
        #pragma unroll
        for (int p = 0; p < 2; p++) {
            int idx = p * 64 + lane;
            int n = idx >> 2, quad = idx & 3;
            bf16x8 row = *(const bf16x8*)&T[n * 40 + quad * 8];
            *(bf16x8*)(dst + (size_t)n * 32 + quad * 8) = row;
        }
    }
}

// ---------------------------------------------------------------------------
// attn_part: R2-proven loop, n-split (unchanged). 256 thr, grid 512.
// ---------------------------------------------------------------------------
__global__ __launch_bounds__(256) void attn_part(const __hip_bfloat16* __restrict__ qT,
                                                 const __hip_bfloat16* __restrict__ kT,
                                                 const __hip_bfloat16* __restrict__ v,
                                                 const float* __restrict__ scal,
                                                 __hip_bfloat16* __restrict__ Opart,
                                                 float* __restrict__ Lsum) {
    __shared__ __hip_bfloat16 Plds[64 * 72];
    __shared__ float Lp[4][32];

    int t = threadIdx.x;
    int wave = t >> 6, lane = t & 63;
    int lo = lane & 31, hi = lane >> 5;

    int blk = blockIdx.x;
    int x8 = blk & 7;
    int b = x8 >> 1;
    int nh = (blk >> 3) & 1;
    int m0 = (((x8 & 1) << 5) + (blk >> 4)) << 6;
    int nbase = nh << 11;

    const __hip_bfloat16* qTb = qT + ((size_t)b << 17);
    const __hip_bfloat16* kTb = kT + ((size_t)b << 17);
    const __hip_bfloat16* vb  = v  + ((size_t)b << 20);

    int mtile_s = wave >> 1, ntile_s = wave & 1;
    int e0w = wave << 6;
    float qkscale = scal[0] * scal[1] * 0.17677669529663687f;

    bf16x8 qf0 = *(const bf16x8*)(qTb + ((size_t)(m0 + mtile_s * 32 + lo)) * 32 + 0  + hi * 8);
    bf16x8 qf1 = *(const bf16x8*)(qTb + ((size_t)(m0 + mtile_s * 32 + lo)) * 32 + 16 + hi * 8);

    f32x16 acc[2][2];
    #pragma unroll
    for (int et = 0; et < 2; et++)
        #pragma unroll
        for (int mt = 0; mt < 2; mt++)
            #pragma unroll
            for (int r = 0; r < 16; r++) acc[et][mt][r] = 0.f;
    float l_acc = 0.f;

    const __hip_bfloat16* krow0 = kTb + (size_t)(ntile_s * 32 + lo) * 32 + hi * 8;
    const __hip_bfloat16* va0b = vb + (size_t)(e0w + lo) * NPOS + hi * 8;
    const __hip_bfloat16* va1b = vb + (size_t)(e0w + 32 + lo) * NPOS + hi * 8;

    for (int s = 0; s < 32; s++) {
        int n0 = nbase + 64 * s;
        const __hip_bfloat16* krow = krow0 + (size_t)n0 * 32;
        bf16x8 kf0 = *(const bf16x8*)(krow);
        bf16x8 kf1 = *(const bf16x8*)(krow + 16);
        f32x16 sv;
        #pragma unroll
        for (int r = 0; r < 16; r++) sv[r] = 0.f;
        sv = __builtin_amdgcn_mfma_f32_32x32x16_bf16(kf0, qf0, sv, 0, 0, 0);
        sv = __builtin_amdgcn_mfma_f32_32x32x16_bf16(kf1, qf1, sv, 0, 0, 0);

        __syncthreads();
        int mrow = mtile_s * 32 + lo;
        #pragma unroll
        for (int g = 0; g < 4; g++) {
            float p0 = __expf(sv[4 * g + 0] * qkscale);
            float p1 = __expf(sv[4 * g + 1] * qkscale);
            float p2 = __expf(sv[4 * g + 2] * qkscale);
            float p3 = __expf(sv[4 * g + 3] * qkscale);
            l_acc += (p0 + p1) + (p2 + p3);
            uint2 pk;
            pk.x = pk2(p0, p1);
            pk.y = pk2(p2, p3);
            int nloc = ntile_s * 32 + 8 * g + 4 * hi;
            *(uint2*)(&Plds[mrow * 72 + nloc]) = pk;
        }
        __syncthreads();

        #pragma unroll
        for (int kc = 0; kc < 4; kc++) {
            bf16x8 pf0 = *(const bf16x8*)(&Plds[(lo)      * 72 + kc * 16 + hi * 8]);
            bf16x8 pf1 = *(const bf16x8*)(&Plds[(32 + lo) * 72 + kc * 16 + hi * 8]);
            bf16x8 vf0 = *(const bf16x8*)(va0b + n0 + kc * 16);
            bf16x8 vf1 = *(const bf16x8*)(va1b + n0 + kc * 16);
            acc[0][0] = __builtin_amdgcn_mfma_f32_32x32x16_bf16(vf0, pf0, acc[0][0], 0, 0, 0);
            acc[0][1] = __builtin_amdgcn_mfma_f32_32x32x16_bf16(vf0, pf1, acc[0][1], 0, 0, 0);
            acc[1][0] = __builtin_amdgcn_mfma_f32_32x32x16_bf16(vf1, pf0, acc[1][0], 0, 0, 0);
            acc[1][1] = __builtin_amdgcn_mfma_f32_32x32x16_bf16(vf1, pf1, acc[1][1], 0, 0, 0);
        }
    }

    float lsum = l_acc + __shfl_xor(l_acc, 32, 64);
    if (lane < 32) Lp[wave][lane] = lsum;
    __syncthreads();
    if (wave == 0) {
        int l2 = lane & 31;
        float Lv = (lane < 32) ? (Lp[0][l2] + Lp[1][l2]) : (Lp[2][l2] + Lp[3][l2]);
        Lsum[(size_t)(nh * 4 + b) * NPOS + m0 + ((lane >> 5) << 5) + l2] = Lv;
    }

    __hip_bfloat16* Ob = Opart + ((size_t)(nh * 4 + b) << 20);
    #pragma unroll
    for (int mt = 0; mt < 2; mt++) {
        int m = m0 + mt * 32 + lo;
        #pragma unroll
        for (int et = 0; et < 2; et++) {
            #pragma unroll
            for (int r = 0; r < 16; r++) {
                int e = e0w + et * 32 + (r & 3) + 8 * (r >> 2) + 4 * hi;
                Ob[(size_t)e * NPOS + m] = __float2bfloat16(acc[et][mt][r]);
            }
        }
    }
}

// ---------------------------------------------------------------------------
// reduce_out: out = x + gamma*sig_v^-1 * (O0+O1)/(L0+L1) (unchanged).
// ---------------------------------------------------------------------------
__global__ __launch_bounds__(256) void reduce_out(const float* __restrict__ x,
                                                  const __hip_bfloat16* __restrict__ Opart,
                                                  const float* __restrict__ Lsum,
                                                  const float* __restrict__ scal,
                                                  const float* __restrict__ gam,
                                                  float* __restrict__ out) {
    int b = blockIdx.z, e = blockIdx.y;
    int m4 = (blockIdx.x * 256 + threadIdx.x) * 4;
    float gs = gam[0] * scal[2];

    size_t o = ((size_t)b << 20) + (size_t)e * NPOS + m4;
    float4 xv = *(const float4*)(x + o);
    const ushort* O0 = (const ushort*)(Opart + ((size_t)b << 20) + (size_t)e * NPOS + m4);
    const ushort* O1 = (const ushort*)(Opart + ((size_t)(4 + b) << 20) + (size_t)e * NPOS + m4);
    ushort4 a0 = *(const ushort4*)O0;
    ushort4 a1 = *(const ushort4*)O1;
    float4 L0 = *(const float4*)(Lsum + (size_t)b * NPOS + m4);
    float4 L1 = *(const float4*)(Lsum + (size_t)(4 + b) * NPOS + m4);

    float4 r;
    r.x = xv.x + gs * (b2f(a0.x) + b2f(a1.x)) / (L0.x + L1.x);
    r.y = xv.y + gs * (b2f(a0.y) + b2f(a1.y)) / (L0.y + L1.y);
    r.z = xv.z + gs * (b2f(a0.z) + b2f(a1.z)) / (L0.z + L1.z);
    r.w = xv.w + gs * (b2f(a0.w) + b2f(a1.w)) / (L0.w + L1.w);
    *(float4*)(out + o) = r;
}

// ---------------------------------------------------------------------------
extern "C" void kernel_launch(void* const* d_in, const int* in_sizes, int n_in,
                              void* d_out, int out_size, void* d_ws, size_t ws_size,
                              hipStream_t stream) {
    const float* x     = (const float*)d_in[0];
    const float* wq    = (const float*)d_in[1];
    const float* wk    = (const float*)d_in[2];
    const float* wv    = (const float*)d_in[3];
    const float* gamma = (const float*)d_in[4];
    float* out = (float*)d_out;

    char* wsb = (char*)d_ws;
    float* scal = (float*)wsb;                           // 256 B
    __hip_bfloat16* qT = (__hip_bfloat16*)(wsb + 256);   // 1 MB
    __hip_bfloat16* kT = qT + ((size_t)4 << 17);         // 1 MB
    __hip_bfloat16* vp = kT + ((size_t)4 << 17);         // 8 MB
    __hip_bfloat16* Opart = vp + ((size_t)4 << 20);      // 16 MB
    float* Lsum = (float*)(Opart + ((size_t)8 << 20));   // 128 KB

    proj_sigma<<<dim3(65, 4), 512, 0, stream>>>(x, wq, wk, wv, qT, kT, vp, scal);
    attn_part<<<512, 256, 0, stream>>>(qT, kT, vp, scal, Opart, Lsum);
    reduce_out<<<dim3(4, 256, 4), 256, 0, stream>>>(x, Opart, Lsum, scal, gamma, out);
}

// Round 10
// 273.038 us; speedup vs baseline: 2.6048x; 1.0724x over previous
//
#include <hip/hip_runtime.h>
#include <hip/hip_bf16.h>
#include <math.h>

// ---------------------------------------------------------------------------
// SelfAttn2d: out = x + gamma * (V @ softmax(Q K^T / sqrt(32))^T)
// B=4, C=256, N=4096, D=32.
// Round 10: wv-sigma micro-opt. R9 localized the 135us to the wv sigma block:
// LDS-issue bound (1024 scalar b16 writebacks/round + 256 scalar b32 x-reads
// per thread per power iter). Fix: symmetric-transposed b64 packed writeback
// (4x fewer write insts), MFMA power iterations with row-frags in registers
// (16 bcast b128 reads/iter), vectorized staging. proj/attn/reduce unchanged.
// ---------------------------------------------------------------------------

#define NPOS 4096
#define XSTR 264   // bf16 row stride for 256-col LDS matrices (33*16B)

typedef __bf16 bf16x8 __attribute__((ext_vector_type(8)));
typedef float  f32x16 __attribute__((ext_vector_type(16)));

static __device__ inline unsigned int pk2(float a, float b) {
    union { __hip_bfloat16 h[2]; unsigned int u; } x;
    x.h[0] = __float2bfloat16(a);
    x.h[1] = __float2bfloat16(b);
    return x.u;
}
static __device__ inline bf16x8 cvt8(float4 a, float4 b) {
    union { bf16x8 v; unsigned int u[4]; } t;
    t.u[0] = pk2(a.x, a.y); t.u[1] = pk2(a.z, a.w);
    t.u[2] = pk2(b.x, b.y); t.u[3] = pk2(b.z, b.w);
    return t.v;
}
static __device__ inline float b2f(unsigned short u) {
    union { float f; unsigned int i; } x;
    x.i = ((unsigned int)u) << 16;
    return x.f;
}

// ---------------------------------------------------------------------------
// proj_sigma: grid (65, 4), 512 thr.
//   blockIdx.x < 64 : proj path (fused MFMA projection)
//   blockIdx.x == 64: sigma path, y=0 -> sigma(wq), 1 -> sigma(wk),
//                     2 -> sigma(wv), 3 -> exit.
// ---------------------------------------------------------------------------
__global__ __launch_bounds__(512) void proj_sigma(const float* __restrict__ x,
                                                  const float* __restrict__ wq,
                                                  const float* __restrict__ wk,
                                                  const float* __restrict__ wv,
                                                  __hip_bfloat16* __restrict__ qT,
                                                  __hip_bfloat16* __restrict__ kT,
                                                  __hip_bfloat16* __restrict__ v,
                                                  float* __restrict__ scal) {
    __shared__ __align__(16) __hip_bfloat16 Wsh[256 * XSTR];  // 135 KB
    __shared__ float wred[16];
    __shared__ __align__(16) __hip_bfloat16 xb[2][256];

    int t = threadIdx.x;
    int wave = t >> 6, lane = t & 63, lo = lane & 31, hi = lane >> 5;

    if (blockIdx.x == 64) {
        // ===================== sigma path =====================
        int sb = blockIdx.y;
        if (sb == 3) return;

        if (sb < 2) {
            // ---- qk: 32x256, single-wave MFMA squaring chain ----
            const float* w = (sb == 0) ? wq : wk;
            __hip_bfloat16* Wb = Wsh;                    // [32][XSTR]
            __hip_bfloat16* As = Wsh + 32 * XSTR;        // [32][40]
            float* xs = (float*)(Wsh + 32 * XSTR + 32 * 40);  // [32] fp32

            if (t < 256) {
                #pragma unroll
                for (int i = 0; i < 8; i++) {
                    int idx4 = t + 256 * i;              // 2048 float4 total
                    int row = idx4 >> 6, c4 = (idx4 & 63) * 4;
                    float4 w4 = *(const float4*)(w + (row << 8) + c4);
                    uint2 pk;
                    pk.x = pk2(w4.x, w4.y);
                    pk.y = pk2(w4.z, w4.w);
                    *(uint2*)&Wb[row * XSTR + c4] = pk;
                }
            }
            __syncthreads();

            if (wave == 0) {
                f32x16 c;
                #pragma unroll
                for (int r = 0; r < 16; r++) c[r] = 0.f;
                for (int kc = 0; kc < 16; kc++) {
                    bf16x8 af = *(const bf16x8*)&Wb[lo * XSTR + kc * 16 + hi * 8];
                    c = __builtin_amdgcn_mfma_f32_32x32x16_bf16(af, af, c, 0, 0, 0);
                }
                for (int sq = 0; sq < 8; sq++) {
                    float dsum = 0.f;
                    #pragma unroll
                    for (int r = 0; r < 16; r++) {
                        int row = (r & 3) + 8 * (r >> 2) + 4 * hi;
                        if (row == lo) dsum += c[r];
                    }
                    #pragma unroll
                    for (int m = 1; m <= 32; m <<= 1) dsum += __shfl_xor(dsum, m, 64);
                    float invt = 1.0f / dsum;
                    #pragma unroll
                    for (int g = 0; g < 4; g++) {
                        // C symmetric: store transposed, packed (col row-run)
                        uint2 pk;
                        pk.x = pk2(c[4 * g + 0] * invt, c[4 * g + 1] * invt);
                        pk.y = pk2(c[4 * g + 2] * invt, c[4 * g + 3] * invt);
                        *(uint2*)&As[lo * 40 + 8 * g + 4 * hi] = pk;
                    }
                    __builtin_amdgcn_s_waitcnt(0);
                    bf16x8 a0 = *(const bf16x8*)&As[lo * 40 + hi * 8];
                    bf16x8 a1 = *(const bf16x8*)&As[lo * 40 + 16 + hi * 8];
                    #pragma unroll
                    for (int r = 0; r < 16; r++) c[r] = 0.f;
                    c = __builtin_amdgcn_mfma_f32_32x32x16_bf16(a0, a0, c, 0, 0, 0);
                    c = __builtin_amdgcn_mfma_f32_32x32x16_bf16(a1, a1, c, 0, 0, 0);
                }
                {
                    float dsum = 0.f;
                    #pragma unroll
                    for (int r = 0; r < 16; r++) {
                        int row = (r & 3) + 8 * (r >> 2) + 4 * hi;
                        if (row == lo) dsum += c[r];
                    }
                    #pragma unroll
                    for (int m = 1; m <= 32; m <<= 1) dsum += __shfl_xor(dsum, m, 64);
                    float invt = 1.0f / dsum;
                    #pragma unroll
                    for (int g = 0; g < 4; g++) {
                        uint2 pk;
                        pk.x = pk2(c[4 * g + 0] * invt, c[4 * g + 1] * invt);
                        pk.y = pk2(c[4 * g + 2] * invt, c[4 * g + 3] * invt);
                        *(uint2*)&As[lo * 40 + 8 * g + 4 * hi] = pk;
                    }
                    __builtin_amdgcn_s_waitcnt(0);
                }
                float xr = 1.0f + 0.01f * lo;
                for (int it = 0; it < 4; it++) {
                    float y = 0.f;
                    #pragma unroll 8
                    for (int j = 0; j < 32; j++) {
                        float xj = __shfl(xr, j, 64);
                        y += b2f(*(const unsigned short*)&As[lo * 40 + j]) * xj;
                    }
                    float ss = y * y;
                    #pragma unroll
                    for (int m = 1; m <= 16; m <<= 1) ss += __shfl_xor(ss, m, 64);
                    xr = y * rsqrtf(ss);
                }
                if (hi == 0) xs[lo] = xr;
            }
            __syncthreads();

            float z = 0.f;
            if (t < 256) {
                #pragma unroll 8
                for (int i = 0; i < 32; i++) z += w[i * 256 + t] * xs[i];
            }
            float zz = z * z;
            #pragma unroll
            for (int m = 1; m <= 32; m <<= 1) zz += __shfl_xor(zz, m, 64);
            if (lane == 0) wred[wave] = zz;
            __syncthreads();
            if (t == 0) {
                float lam = 0.f;
                for (int i = 0; i < 8; i++) lam += wred[i];
                scal[sb] = rsqrtf(lam);
            }
            return;
        }

        // ---- wv: 256x256 Gram^64 chain on MFMA ----
        int p = wave >> 1;   // m-tile pair
        int q = wave & 1;    // j-half

        // staging: fp32 -> bf16, float4 reads + b64 packed LDS writes
        #pragma unroll
        for (int i = 0; i < 32; i++) {
            int idx4 = t + 512 * i;                  // 16384 float4 total
            int row = idx4 >> 6, c4 = (idx4 & 63) * 4;
            float4 w4 = *(const float4*)(wv + ((size_t)row << 8) + c4);
            uint2 pk;
            pk.x = pk2(w4.x, w4.y);
            pk.y = pk2(w4.z, w4.w);
            *(uint2*)&Wsh[row * XSTR + c4] = pk;
        }
        __syncthreads();

        for (int round = 0; round < 7; round++) {
            f32x16 c[2][4];
            #pragma unroll
            for (int mt = 0; mt < 2; mt++)
                #pragma unroll
                for (int j = 0; j < 4; j++)
                    #pragma unroll
                    for (int r = 0; r < 16; r++) c[mt][j][r] = 0.f;

            for (int kc = 0; kc < 16; kc++) {
                bf16x8 af[2], bfj[4];
                #pragma unroll
                for (int mt = 0; mt < 2; mt++)
                    af[mt] = *(const bf16x8*)&Wsh[((2 * p + mt) * 32 + lo) * XSTR + kc * 16 + hi * 8];
                #pragma unroll
                for (int j = 0; j < 4; j++)
                    bfj[j] = *(const bf16x8*)&Wsh[((4 * q + j) * 32 + lo) * XSTR + kc * 16 + hi * 8];
                #pragma unroll
                for (int mt = 0; mt < 2; mt++)
                    #pragma unroll
                    for (int j = 0; j < 4; j++)
                        c[mt][j] = __builtin_amdgcn_mfma_f32_32x32x16_bf16(af[mt], bfj[j], c[mt][j], 0, 0, 0);
            }

            // trace via shuffle + one barrier
            float dsum = 0.f;
            #pragma unroll
            for (int mt = 0; mt < 2; mt++) {
                int Tm = 2 * p + mt;
                if ((Tm >> 2) == q) {
                    int j = Tm - 4 * q;
                    #pragma unroll
                    for (int r = 0; r < 16; r++) {
                        int row = (r & 3) + 8 * (r >> 2) + 4 * hi;
                        if (row == lo) dsum += c[mt][j][r];
                    }
                }
            }
            #pragma unroll
            for (int m = 1; m <= 32; m <<= 1) dsum += __shfl_xor(dsum, m, 64);
            if (lane == 0) wred[wave] = dsum;
            __syncthreads();   // Wsh reads done + wred visible
            float tr = 0.f;
            for (int i = 0; i < 8; i++) tr += wred[i];
            float invt = 1.0f / tr;

            // C symmetric: write C^T with packed b64 (4 consecutive rows/reg-quad)
            #pragma unroll
            for (int mt = 0; mt < 2; mt++)
                #pragma unroll
                for (int j = 0; j < 4; j++) {
                    int base = ((4 * q + j) * 32 + lo) * XSTR + (2 * p + mt) * 32 + 4 * hi;
                    #pragma unroll
                    for (int g = 0; g < 4; g++) {
                        uint2 pk;
                        pk.x = pk2(c[mt][j][4 * g + 0] * invt, c[mt][j][4 * g + 1] * invt);
                        pk.y = pk2(c[mt][j][4 * g + 2] * invt, c[mt][j][4 * g + 3] * invt);
                        *(uint2*)&Wsh[base + 8 * g] = pk;
                    }
                }
            __syncthreads();
        }

        // ---- 8 power iterations via MFMA, A row-frags in registers ----
        bf16x8 af[16];
        #pragma unroll
        for (int kc = 0; kc < 16; kc++)
            af[kc] = *(const bf16x8*)&Wsh[(wave * 32 + lo) * XSTR + kc * 16 + hi * 8];

        if (t < 256) xb[0][t] = __float2bfloat16(1.0f + 0.01f * t);
        __syncthreads();

        for (int it = 0; it < 8; it++) {
            int cur = it & 1;
            f32x16 c;
            #pragma unroll
            for (int r = 0; r < 16; r++) c[r] = 0.f;
            #pragma unroll
            for (int kc = 0; kc < 16; kc++) {
                bf16x8 bfx = *(const bf16x8*)&xb[cur][kc * 16 + hi * 8];  // broadcast
                c = __builtin_amdgcn_mfma_f32_32x32x16_bf16(af[kc], bfx, c, 0, 0, 0);
            }
            if (lo == 0) {
                #pragma unroll
                for (int g = 0; g < 4; g++) {
                    uint2 pk;
                    pk.x = pk2(c[4 * g + 0], c[4 * g + 1]);
                    pk.y = pk2(c[4 * g + 2], c[4 * g + 3]);
                    *(uint2*)&xb[cur ^ 1][wave * 32 + 8 * g + 4 * hi] = pk;
                }
            }
            __syncthreads();
        }

        // ---- Rayleigh fp32 vs exact G: sigma^2 = ||wv^T x||^2 / ||x||^2 ----
        float z = 0.f, xt = 0.f;
        if (t < 256) {
            xt = b2f(*(const unsigned short*)&xb[0][t]);
            for (int i = 0; i < 256; i++)
                z += wv[i * 256 + t] * b2f(*(const unsigned short*)&xb[0][i]);
        }
        float zz = z * z, ss = xt * xt;
        #pragma unroll
        for (int m = 1; m <= 32; m <<= 1) {
            zz += __shfl_xor(zz, m, 64);
            ss += __shfl_xor(ss, m, 64);
        }
        if (lane == 0) { wred[wave] = zz; wred[8 + wave] = ss; }
        __syncthreads();
        if (t == 0) {
            float ZZ = 0.f, SS = 0.f;
            for (int i = 0; i < 8; i++) { ZZ += wred[i]; SS += wred[8 + i]; }
            scal[2] = sqrtf(SS / ZZ);
        }
        return;
    }

    // ===================== proj path (unchanged logic) =====================
    __hip_bfloat16* XT  = Wsh;                 // [64][XSTR] = 33.8 KB
    __hip_bfloat16* TqB = Wsh + 64 * XSTR;     // 4 x [32*40] = 10 KB

    int n0 = blockIdx.x * 64;
    int b = blockIdx.y;
    const float* xb2 = x + ((size_t)b << 20);

    {
        int nl = t & 63, cg = t >> 6;
        #pragma unroll 8
        for (int i = 0; i < 32; i++) {
            int c = cg * 32 + i;
            XT[nl * XSTR + c] = __float2bfloat16(xb2[(size_t)c * NPOS + n0 + nl]);
        }
    }
    __syncthreads();

    f32x16 accv[2], accq;
    #pragma unroll
    for (int it = 0; it < 2; it++)
        #pragma unroll
        for (int r = 0; r < 16; r++) accv[it][r] = 0.f;
    #pragma unroll
    for (int r = 0; r < 16; r++) accq[r] = 0.f;

    const float* wvrow = wv + (size_t)(wave * 32 + lo) * 256 + hi * 8;
    const float* wqkrow = ((wave < 2) ? wq : wk) + (size_t)lo * 256 + hi * 8;
    int qk_it = wave & 1;

    for (int kc = 0; kc < 16; kc++) {
        bf16x8 af0 = *(const bf16x8*)&XT[lo * XSTR + kc * 16 + hi * 8];
        bf16x8 af1 = *(const bf16x8*)&XT[(32 + lo) * XSTR + kc * 16 + hi * 8];
        float4 wa = *(const float4*)(wvrow + kc * 16);
        float4 wb = *(const float4*)(wvrow + kc * 16 + 4);
        bf16x8 bfv = cvt8(wa, wb);
        accv[0] = __builtin_amdgcn_mfma_f32_32x32x16_bf16(af0, bfv, accv[0], 0, 0, 0);
        accv[1] = __builtin_amdgcn_mfma_f32_32x32x16_bf16(af1, bfv, accv[1], 0, 0, 0);
        if (wave < 4) {
            float4 qa = *(const float4*)(wqkrow + kc * 16);
            float4 qb = *(const float4*)(wqkrow + kc * 16 + 4);
            bf16x8 bfq = cvt8(qa, qb);
            accq = __builtin_amdgcn_mfma_f32_32x32x16_bf16(qk_it ? af1 : af0, bfq, accq, 0, 0, 0);
        }
    }

    __hip_bfloat16* vbb = v + ((size_t)b << 20) + (size_t)(wave * 32 + lo) * NPOS + n0;
    #pragma unroll
    for (int it = 0; it < 2; it++)
        #pragma unroll
        for (int g = 0; g < 4; g++) {
            uint2 pk;
            pk.x = pk2(accv[it][4 * g + 0], accv[it][4 * g + 1]);
            pk.y = pk2(accv[it][4 * g + 2], accv[it][4 * g + 3]);
            *(uint2*)(vbb + it * 32 + 8 * g + 4 * hi) = pk;
        }

    if (wave < 4) {
        __hip_bfloat16* T = TqB + wave * (32 * 40);
        #pragma unroll
        for (int r = 0; r < 16; r++) {
            int n = (r & 3) + 8 * (r >> 2) + 4 * hi;
            T[n * 40 + lo] = __float2bfloat16(accq[r]);
        }
    }
    __syncthreads();
    if (wave < 4) {
        __hip_bfloat16* T = TqB + wave * (32 * 40);
        __hip_bfloat16* dst = ((wave < 2) ? qT : kT) + ((size_t)b << 17)
                              + (size_t)(n0 + qk_it * 32) * 32;
        #pragma unroll
        for (int p = 0; p < 2; p++) {
            int idx = p * 64 + lane;
            int n = idx >> 2, quad = idx & 3;
            bf16x8 row = *(const bf16x8*)&T[n * 40 + quad * 8];
            *(bf16x8*)(dst + (size_t)n * 32 + quad * 8) = row;
        }
    }
}

// ---------------------------------------------------------------------------
// attn_part: R2-proven loop, n-split (unchanged). 256 thr, grid 512.
// ---------------------------------------------------------------------------
__global__ __launch_bounds__(256) void attn_part(const __hip_bfloat16* __restrict__ qT,
                                                 const __hip_bfloat16* __restrict__ kT,
                                                 const __hip_bfloat16* __restrict__ v,
                                                 const float* __restrict__ scal,
                                                 __hip_bfloat16* __restrict__ Opart,
                                                 float* __restrict__ Lsum) {
    __shared__ __hip_bfloat16 Plds[64 * 72];
    __shared__ float Lp[4][32];

    int t = threadIdx.x;
    int wave = t >> 6, lane = t & 63;
    int lo = lane & 31, hi = lane >> 5;

    int blk = blockIdx.x;
    int x8 = blk & 7;
    int b = x8 >> 1;
    int nh = (blk >> 3) & 1;
    int m0 = (((x8 & 1) << 5) + (blk >> 4)) << 6;
    int nbase = nh << 11;

    const __hip_bfloat16* qTb = qT + ((size_t)b << 17);
    const __hip_bfloat16* kTb = kT + ((size_t)b << 17);
    const __hip_bfloat16* vb  = v  + ((size_t)b << 20);

    int mtile_s = wave >> 1, ntile_s = wave & 1;
    int e0w = wave << 6;
    float qkscale = scal[0] * scal[1] * 0.17677669529663687f;

    bf16x8 qf0 = *(const bf16x8*)(qTb + ((size_t)(m0 + mtile_s * 32 + lo)) * 32 + 0  + hi * 8);
    bf16x8 qf1 = *(const bf16x8*)(qTb + ((size_t)(m0 + mtile_s * 32 + lo)) * 32 + 16 + hi * 8);

    f32x16 acc[2][2];
    #pragma unroll
    for (int et = 0; et < 2; et++)
        #pragma unroll
        for (int mt = 0; mt < 2; mt++)
            #pragma unroll
            for (int r = 0; r < 16; r++) acc[et][mt][r] = 0.f;
    float l_acc = 0.f;

    const __hip_bfloat16* krow0 = kTb + (size_t)(ntile_s * 32 + lo) * 32 + hi * 8;
    const __hip_bfloat16* va0b = vb + (size_t)(e0w + lo) * NPOS + hi * 8;
    const __hip_bfloat16* va1b = vb + (size_t)(e0w + 32 + lo) * NPOS + hi * 8;

    for (int s = 0; s < 32; s++) {
        int n0 = nbase + 64 * s;
        const __hip_bfloat16* krow = krow0 + (size_t)n0 * 32;
        bf16x8 kf0 = *(const bf16x8*)(krow);
        bf16x8 kf1 = *(const bf16x8*)(krow + 16);
        f32x16 sv;
        #pragma unroll
        for (int r = 0; r < 16; r++) sv[r] = 0.f;
        sv = __builtin_amdgcn_mfma_f32_32x32x16_bf16(kf0, qf0, sv, 0, 0, 0);
        sv = __builtin_amdgcn_mfma_f32_32x32x16_bf16(kf1, qf1, sv, 0, 0, 0);

        __syncthreads();
        int mrow = mtile_s * 32 + lo;
        #pragma unroll
        for (int g = 0; g < 4; g++) {
            float p0 = __expf(sv[4 * g + 0] * qkscale);
            float p1 = __expf(sv[4 * g + 1] * qkscale);
            float p2 = __expf(sv[4 * g + 2] * qkscale);
            float p3 = __expf(sv[4 * g + 3] * qkscale);
            l_acc += (p0 + p1) + (p2 + p3);
            uint2 pk;
            pk.x = pk2(p0, p1);
            pk.y = pk2(p2, p3);
            int nloc = ntile_s * 32 + 8 * g + 4 * hi;
            *(uint2*)(&Plds[mrow * 72 + nloc]) = pk;
        }
        __syncthreads();

        #pragma unroll
        for (int kc = 0; kc < 4; kc++) {
            bf16x8 pf0 = *(const bf16x8*)(&Plds[(lo)      * 72 + kc * 16 + hi * 8]);
            bf16x8 pf1 = *(const bf16x8*)(&Plds[(32 + lo) * 72 + kc * 16 + hi * 8]);
            bf16x8 vf0 = *(const bf16x8*)(va0b + n0 + kc * 16);
            bf16x8 vf1 = *(const bf16x8*)(va1b + n0 + kc * 16);
            acc[0][0] = __builtin_amdgcn_mfma_f32_32x32x16_bf16(vf0, pf0, acc[0][0], 0, 0, 0);
            acc[0][1] = __builtin_amdgcn_mfma_f32_32x32x16_bf16(vf0, pf1, acc[0][1], 0, 0, 0);
            acc[1][0] = __builtin_amdgcn_mfma_f32_32x32x16_bf16(vf1, pf0, acc[1][0], 0, 0, 0);
            acc[1][1] = __builtin_amdgcn_mfma_f32_32x32x16_bf16(vf1, pf1, acc[1][1], 0, 0, 0);
        }
    }

    float lsum = l_acc + __shfl_xor(l_acc, 32, 64);
    if (lane < 32) Lp[wave][lane] = lsum;
    __syncthreads();
    if (wave == 0) {
        int l2 = lane & 31;
        float Lv = (lane < 32) ? (Lp[0][l2] + Lp[1][l2]) : (Lp[2][l2] + Lp[3][l2]);
        Lsum[(size_t)(nh * 4 + b) * NPOS + m0 + ((lane >> 5) << 5) + l2] = Lv;
    }

    __hip_bfloat16* Ob = Opart + ((size_t)(nh * 4 + b) << 20);
    #pragma unroll
    for (int mt = 0; mt < 2; mt++) {
        int m = m0 + mt * 32 + lo;
        #pragma unroll
        for (int et = 0; et < 2; et++) {
            #pragma unroll
            for (int r = 0; r < 16; r++) {
                int e = e0w + et * 32 + (r & 3) + 8 * (r >> 2) + 4 * hi;
                Ob[(size_t)e * NPOS + m] = __float2bfloat16(acc[et][mt][r]);
            }
        }
    }
}

// ---------------------------------------------------------------------------
// reduce_out: out = x + gamma*sig_v^-1 * (O0+O1)/(L0+L1) (unchanged).
// ---------------------------------------------------------------------------
__global__ __launch_bounds__(256) void reduce_out(const float* __restrict__ x,
                                                  const __hip_bfloat16* __restrict__ Opart,
                                                  const float* __restrict__ Lsum,
                                                  const float* __restrict__ scal,
                                                  const float* __restrict__ gam,
                                                  float* __restrict__ out) {
    int b = blockIdx.z, e = blockIdx.y;
    int m4 = (blockIdx.x * 256 + threadIdx.x) * 4;
    float gs = gam[0] * scal[2];

    size_t o = ((size_t)b << 20) + (size_t)e * NPOS + m4;
    float4 xv = *(const float4*)(x + o);
    const ushort* O0 = (const ushort*)(Opart + ((size_t)b << 20) + (size_t)e * NPOS + m4);
    const ushort* O1 = (const ushort*)(Opart + ((size_t)(4 + b) << 20) + (size_t)e * NPOS + m4);
    ushort4 a0 = *(const ushort4*)O0;
    ushort4 a1 = *(const ushort4*)O1;
    float4 L0 = *(const float4*)(Lsum + (size_t)b * NPOS + m4);
    float4 L1 = *(const float4*)(Lsum + (size_t)(4 + b) * NPOS + m4);

    float4 r;
    r.x = xv.x + gs * (b2f(a0.x) + b2f(a1.x)) / (L0.x + L1.x);
    r.y = xv.y + gs * (b2f(a0.y) + b2f(a1.y)) / (L0.y + L1.y);
    r.z = xv.z + gs * (b2f(a0.z) + b2f(a1.z)) / (L0.z + L1.z);
    r.w = xv.w + gs * (b2f(a0.w) + b2f(a1.w)) / (L0.w + L1.w);
    *(float4*)(out + o) = r;
}

// ---------------------------------------------------------------------------
extern "C" void kernel_launch(void* const* d_in, const int* in_sizes, int n_in,
                              void* d_out, int out_size, void* d_ws, size_t ws_size,
                              hipStream_t stream) {
    const float* x     = (const float*)d_in[0];
    const float* wq    = (const float*)d_in[1];
    const float* wk    = (const float*)d_in[2];
    const float* wv    = (const float*)d_in[3];
    const float* gamma = (const float*)d_in[4];
    float* out = (float*)d_out;

    char* wsb = (char*)d_ws;
    float* scal = (float*)wsb;                           // 256 B
    __hip_bfloat16* qT = (__hip_bfloat16*)(wsb + 256);   // 1 MB
    __hip_bfloat16* kT = qT + ((size_t)4 << 17);         // 1 MB
    __hip_bfloat16* vp = kT + ((size_t)4 << 17);         // 8 MB
    __hip_bfloat16* Opart = vp + ((size_t)4 << 20);      // 16 MB
    float* Lsum = (float*)(Opart + ((size_t)8 << 20));   // 128 KB

    proj_sigma<<<dim3(65, 4), 512, 0, stream>>>(x, wq, wk, wv, qT, kT, vp, scal);
    attn_part<<<512, 256, 0, stream>>>(qT, kT, vp, scal, Opart, Lsum);
    reduce_out<<<dim3(4, 256, 4), 256, 0, stream>>>(x, Opart, Lsum, scal, gamma, out);
}

// Round 11
// 249.656 us; speedup vs baseline: 2.8488x; 1.0937x over previous
//
#include <hip/hip_runtime.h>
#include <hip/hip_bf16.h>
#include <math.h>

// ---------------------------------------------------------------------------
// SelfAttn2d: out = x + gamma * (V @ softmax(Q K^T / sqrt(32))^T)
// B=4, C=256, N=4096, D=32.
// Round 11: (1) wv sigma serial chain trimmed (5 squarings + 4 MFMA power
// iters; R9/R10 showed wall time tracks chain length on the idle-clock tail),
// (2) attn_part n-split 2->4 (grid 1024, 16 steps) for 3 blocks/CU TLP,
// (3) reduce_out sums 4 partials.
// ---------------------------------------------------------------------------

#define NPOS 4096
#define XSTR 264   // bf16 row stride for 256-col LDS matrices (33*16B)

typedef __bf16 bf16x8 __attribute__((ext_vector_type(8)));
typedef float  f32x16 __attribute__((ext_vector_type(16)));

static __device__ inline unsigned int pk2(float a, float b) {
    union { __hip_bfloat16 h[2]; unsigned int u; } x;
    x.h[0] = __float2bfloat16(a);
    x.h[1] = __float2bfloat16(b);
    return x.u;
}
static __device__ inline bf16x8 cvt8(float4 a, float4 b) {
    union { bf16x8 v; unsigned int u[4]; } t;
    t.u[0] = pk2(a.x, a.y); t.u[1] = pk2(a.z, a.w);
    t.u[2] = pk2(b.x, b.y); t.u[3] = pk2(b.z, b.w);
    return t.v;
}
static __device__ inline float b2f(unsigned short u) {
    union { float f; unsigned int i; } x;
    x.i = ((unsigned int)u) << 16;
    return x.f;
}

// ---------------------------------------------------------------------------
// proj_sigma: grid (65, 4), 512 thr.
//   blockIdx.x < 64 : proj path (fused MFMA projection)
//   blockIdx.x == 64: sigma path, y=0 -> sigma(wq), 1 -> sigma(wk),
//                     2 -> sigma(wv), 3 -> exit.
// ---------------------------------------------------------------------------
__global__ __launch_bounds__(512) void proj_sigma(const float* __restrict__ x,
                                                  const float* __restrict__ wq,
                                                  const float* __restrict__ wk,
                                                  const float* __restrict__ wv,
                                                  __hip_bfloat16* __restrict__ qT,
                                                  __hip_bfloat16* __restrict__ kT,
                                                  __hip_bfloat16* __restrict__ v,
                                                  float* __restrict__ scal) {
    __shared__ __align__(16) __hip_bfloat16 Wsh[256 * XSTR];  // 135 KB
    __shared__ float wred[16];
    __shared__ __align__(16) __hip_bfloat16 xb[2][256];

    int t = threadIdx.x;
    int wave = t >> 6, lane = t & 63, lo = lane & 31, hi = lane >> 5;

    if (blockIdx.x == 64) {
        // ===================== sigma path =====================
        int sb = blockIdx.y;
        if (sb == 3) return;

        if (sb < 2) {
            // ---- qk: 32x256, single-wave MFMA squaring chain ----
            const float* w = (sb == 0) ? wq : wk;
            __hip_bfloat16* Wb = Wsh;                    // [32][XSTR]
            __hip_bfloat16* As = Wsh + 32 * XSTR;        // [32][40]
            float* xs = (float*)(Wsh + 32 * XSTR + 32 * 40);  // [32] fp32

            if (t < 256) {
                #pragma unroll
                for (int i = 0; i < 8; i++) {
                    int idx4 = t + 256 * i;              // 2048 float4 total
                    int row = idx4 >> 6, c4 = (idx4 & 63) * 4;
                    float4 w4 = *(const float4*)(w + (row << 8) + c4);
                    uint2 pk;
                    pk.x = pk2(w4.x, w4.y);
                    pk.y = pk2(w4.z, w4.w);
                    *(uint2*)&Wb[row * XSTR + c4] = pk;
                }
            }
            __syncthreads();

            if (wave == 0) {
                f32x16 c;
                #pragma unroll
                for (int r = 0; r < 16; r++) c[r] = 0.f;
                for (int kc = 0; kc < 16; kc++) {
                    bf16x8 af = *(const bf16x8*)&Wb[lo * XSTR + kc * 16 + hi * 8];
                    c = __builtin_amdgcn_mfma_f32_32x32x16_bf16(af, af, c, 0, 0, 0);
                }
                for (int sq = 0; sq < 8; sq++) {
                    float dsum = 0.f;
                    #pragma unroll
                    for (int r = 0; r < 16; r++) {
                        int row = (r & 3) + 8 * (r >> 2) + 4 * hi;
                        if (row == lo) dsum += c[r];
                    }
                    #pragma unroll
                    for (int m = 1; m <= 32; m <<= 1) dsum += __shfl_xor(dsum, m, 64);
                    float invt = 1.0f / dsum;
                    #pragma unroll
                    for (int g = 0; g < 4; g++) {
                        uint2 pk;
                        pk.x = pk2(c[4 * g + 0] * invt, c[4 * g + 1] * invt);
                        pk.y = pk2(c[4 * g + 2] * invt, c[4 * g + 3] * invt);
                        *(uint2*)&As[lo * 40 + 8 * g + 4 * hi] = pk;
                    }
                    __builtin_amdgcn_s_waitcnt(0);
                    bf16x8 a0 = *(const bf16x8*)&As[lo * 40 + hi * 8];
                    bf16x8 a1 = *(const bf16x8*)&As[lo * 40 + 16 + hi * 8];
                    #pragma unroll
                    for (int r = 0; r < 16; r++) c[r] = 0.f;
                    c = __builtin_amdgcn_mfma_f32_32x32x16_bf16(a0, a0, c, 0, 0, 0);
                    c = __builtin_amdgcn_mfma_f32_32x32x16_bf16(a1, a1, c, 0, 0, 0);
                }
                {
                    float dsum = 0.f;
                    #pragma unroll
                    for (int r = 0; r < 16; r++) {
                        int row = (r & 3) + 8 * (r >> 2) + 4 * hi;
                        if (row == lo) dsum += c[r];
                    }
                    #pragma unroll
                    for (int m = 1; m <= 32; m <<= 1) dsum += __shfl_xor(dsum, m, 64);
                    float invt = 1.0f / dsum;
                    #pragma unroll
                    for (int g = 0; g < 4; g++) {
                        uint2 pk;
                        pk.x = pk2(c[4 * g + 0] * invt, c[4 * g + 1] * invt);
                        pk.y = pk2(c[4 * g + 2] * invt, c[4 * g + 3] * invt);
                        *(uint2*)&As[lo * 40 + 8 * g + 4 * hi] = pk;
                    }
                    __builtin_amdgcn_s_waitcnt(0);
                }
                float xr = 1.0f + 0.01f * lo;
                for (int it = 0; it < 4; it++) {
                    float y = 0.f;
                    #pragma unroll 8
                    for (int j = 0; j < 32; j++) {
                        float xj = __shfl(xr, j, 64);
                        y += b2f(*(const unsigned short*)&As[lo * 40 + j]) * xj;
                    }
                    float ss = y * y;
                    #pragma unroll
                    for (int m = 1; m <= 16; m <<= 1) ss += __shfl_xor(ss, m, 64);
                    xr = y * rsqrtf(ss);
                }
                if (hi == 0) xs[lo] = xr;
            }
            __syncthreads();

            float z = 0.f;
            if (t < 256) {
                #pragma unroll 8
                for (int i = 0; i < 32; i++) z += w[i * 256 + t] * xs[i];
            }
            float zz = z * z;
            #pragma unroll
            for (int m = 1; m <= 32; m <<= 1) zz += __shfl_xor(zz, m, 64);
            if (lane == 0) wred[wave] = zz;
            __syncthreads();
            if (t == 0) {
                float lam = 0.f;
                for (int i = 0; i < 8; i++) lam += wred[i];
                scal[sb] = rsqrtf(lam);
            }
            return;
        }

        // ---- wv: 256x256 Gram^32 chain on MFMA (5 squarings) ----
        int p = wave >> 1;   // m-tile pair
        int q = wave & 1;    // j-half

        #pragma unroll
        for (int i = 0; i < 32; i++) {
            int idx4 = t + 512 * i;                  // 16384 float4 total
            int row = idx4 >> 6, c4 = (idx4 & 63) * 4;
            float4 w4 = *(const float4*)(wv + ((size_t)row << 8) + c4);
            uint2 pk;
            pk.x = pk2(w4.x, w4.y);
            pk.y = pk2(w4.z, w4.w);
            *(uint2*)&Wsh[row * XSTR + c4] = pk;
        }
        __syncthreads();

        for (int round = 0; round < 5; round++) {
            f32x16 c[2][4];
            #pragma unroll
            for (int mt = 0; mt < 2; mt++)
                #pragma unroll
                for (int j = 0; j < 4; j++)
                    #pragma unroll
                    for (int r = 0; r < 16; r++) c[mt][j][r] = 0.f;

            for (int kc = 0; kc < 16; kc++) {
                bf16x8 af[2], bfj[4];
                #pragma unroll
                for (int mt = 0; mt < 2; mt++)
                    af[mt] = *(const bf16x8*)&Wsh[((2 * p + mt) * 32 + lo) * XSTR + kc * 16 + hi * 8];
                #pragma unroll
                for (int j = 0; j < 4; j++)
                    bfj[j] = *(const bf16x8*)&Wsh[((4 * q + j) * 32 + lo) * XSTR + kc * 16 + hi * 8];
                #pragma unroll
                for (int mt = 0; mt < 2; mt++)
                    #pragma unroll
                    for (int j = 0; j < 4; j++)
                        c[mt][j] = __builtin_amdgcn_mfma_f32_32x32x16_bf16(af[mt], bfj[j], c[mt][j], 0, 0, 0);
            }

            float dsum = 0.f;
            #pragma unroll
            for (int mt = 0; mt < 2; mt++) {
                int Tm = 2 * p + mt;
                if ((Tm >> 2) == q) {
                    int j = Tm - 4 * q;
                    #pragma unroll
                    for (int r = 0; r < 16; r++) {
                        int row = (r & 3) + 8 * (r >> 2) + 4 * hi;
                        if (row == lo) dsum += c[mt][j][r];
                    }
                }
            }
            #pragma unroll
            for (int m = 1; m <= 32; m <<= 1) dsum += __shfl_xor(dsum, m, 64);
            if (lane == 0) wred[wave] = dsum;
            __syncthreads();   // Wsh reads done + wred visible
            float tr = 0.f;
            for (int i = 0; i < 8; i++) tr += wred[i];
            float invt = 1.0f / tr;

            // C symmetric: write C^T with packed b64
            #pragma unroll
            for (int mt = 0; mt < 2; mt++)
                #pragma unroll
                for (int j = 0; j < 4; j++) {
                    int base = ((4 * q + j) * 32 + lo) * XSTR + (2 * p + mt) * 32 + 4 * hi;
                    #pragma unroll
                    for (int g = 0; g < 4; g++) {
                        uint2 pk;
                        pk.x = pk2(c[mt][j][4 * g + 0] * invt, c[mt][j][4 * g + 1] * invt);
                        pk.y = pk2(c[mt][j][4 * g + 2] * invt, c[mt][j][4 * g + 3] * invt);
                        *(uint2*)&Wsh[base + 8 * g] = pk;
                    }
                }
            __syncthreads();
        }

        // ---- 4 power iterations via MFMA, A row-frags in registers ----
        bf16x8 af[16];
        #pragma unroll
        for (int kc = 0; kc < 16; kc++)
            af[kc] = *(const bf16x8*)&Wsh[(wave * 32 + lo) * XSTR + kc * 16 + hi * 8];

        if (t < 256) xb[0][t] = __float2bfloat16(1.0f + 0.01f * t);
        __syncthreads();

        for (int it = 0; it < 4; it++) {
            int cur = it & 1;
            f32x16 c;
            #pragma unroll
            for (int r = 0; r < 16; r++) c[r] = 0.f;
            #pragma unroll
            for (int kc = 0; kc < 16; kc++) {
                bf16x8 bfx = *(const bf16x8*)&xb[cur][kc * 16 + hi * 8];  // broadcast
                c = __builtin_amdgcn_mfma_f32_32x32x16_bf16(af[kc], bfx, c, 0, 0, 0);
            }
            if (lo == 0) {
                #pragma unroll
                for (int g = 0; g < 4; g++) {
                    uint2 pk;
                    pk.x = pk2(c[4 * g + 0], c[4 * g + 1]);
                    pk.y = pk2(c[4 * g + 2], c[4 * g + 3]);
                    *(uint2*)&xb[cur ^ 1][wave * 32 + 8 * g + 4 * hi] = pk;
                }
            }
            __syncthreads();
        }

        // ---- Rayleigh fp32 vs exact G: sigma^2 = ||wv^T x||^2 / ||x||^2 ----
        float z = 0.f, xt = 0.f;
        if (t < 256) {
            xt = b2f(*(const unsigned short*)&xb[0][t]);
            for (int i = 0; i < 256; i++)
                z += wv[i * 256 + t] * b2f(*(const unsigned short*)&xb[0][i]);
        }
        float zz = z * z, ss = xt * xt;
        #pragma unroll
        for (int m = 1; m <= 32; m <<= 1) {
            zz += __shfl_xor(zz, m, 64);
            ss += __shfl_xor(ss, m, 64);
        }
        if (lane == 0) { wred[wave] = zz; wred[8 + wave] = ss; }
        __syncthreads();
        if (t == 0) {
            float ZZ = 0.f, SS = 0.f;
            for (int i = 0; i < 8; i++) { ZZ += wred[i]; SS += wred[8 + i]; }
            scal[2] = sqrtf(SS / ZZ);
        }
        return;
    }

    // ===================== proj path (unchanged logic) =====================
    __hip_bfloat16* XT  = Wsh;                 // [64][XSTR] = 33.8 KB
    __hip_bfloat16* TqB = Wsh + 64 * XSTR;     // 4 x [32*40] = 10 KB

    int n0 = blockIdx.x * 64;
    int b = blockIdx.y;
    const float* xb2 = x + ((size_t)b << 20);

    {
        int nl = t & 63, cg = t >> 6;
        #pragma unroll 8
        for (int i = 0; i < 32; i++) {
            int c = cg * 32 + i;
            XT[nl * XSTR + c] = __float2bfloat16(xb2[(size_t)c * NPOS + n0 + nl]);
        }
    }
    __syncthreads();

    f32x16 accv[2], accq;
    #pragma unroll
    for (int it = 0; it < 2; it++)
        #pragma unroll
        for (int r = 0; r < 16; r++) accv[it][r] = 0.f;
    #pragma unroll
    for (int r = 0; r < 16; r++) accq[r] = 0.f;

    const float* wvrow = wv + (size_t)(wave * 32 + lo) * 256 + hi * 8;
    const float* wqkrow = ((wave < 2) ? wq : wk) + (size_t)lo * 256 + hi * 8;
    int qk_it = wave & 1;

    for (int kc = 0; kc < 16; kc++) {
        bf16x8 af0 = *(const bf16x8*)&XT[lo * XSTR + kc * 16 + hi * 8];
        bf16x8 af1 = *(const bf16x8*)&XT[(32 + lo) * XSTR + kc * 16 + hi * 8];
        float4 wa = *(const float4*)(wvrow + kc * 16);
        float4 wb = *(const float4*)(wvrow + kc * 16 + 4);
        bf16x8 bfv = cvt8(wa, wb);
        accv[0] = __builtin_amdgcn_mfma_f32_32x32x16_bf16(af0, bfv, accv[0], 0, 0, 0);
        accv[1] = __builtin_amdgcn_mfma_f32_32x32x16_bf16(af1, bfv, accv[1], 0, 0, 0);
        if (wave < 4) {
            float4 qa = *(const float4*)(wqkrow + kc * 16);
            float4 qb = *(const float4*)(wqkrow + kc * 16 + 4);
            bf16x8 bfq = cvt8(qa, qb);
            accq = __builtin_amdgcn_mfma_f32_32x32x16_bf16(qk_it ? af1 : af0, bfq, accq, 0, 0, 0);
        }
    }

    __hip_bfloat16* vbb = v + ((size_t)b << 20) + (size_t)(wave * 32 + lo) * NPOS + n0;
    #pragma unroll
    for (int it = 0; it < 2; it++)
        #pragma unroll
        for (int g = 0; g < 4; g++) {
            uint2 pk;
            pk.x = pk2(accv[it][4 * g + 0], accv[it][4 * g + 1]);
            pk.y = pk2(accv[it][4 * g + 2], accv[it][4 * g + 3]);
            *(uint2*)(vbb + it * 32 + 8 * g + 4 * hi) = pk;
        }

    if (wave < 4) {
        __hip_bfloat16* T = TqB + wave * (32 * 40);
        #pragma unroll
        for (int r = 0; r < 16; r++) {
            int n = (r & 3) + 8 * (r >> 2) + 4 * hi;
            T[n * 40 + lo] = __float2bfloat16(accq[r]);
        }
    }
    __syncthreads();
    if (wave < 4) {
        __hip_bfloat16* T = TqB + wave * (32 * 40);
        __hip_bfloat16* dst = ((wave < 2) ? qT : kT) + ((size_t)b << 17)
                              + (size_t)(n0 + qk_it * 32) * 32;
        #pragma unroll
        for (int p = 0; p < 2; p++) {
            int idx = p * 64 + lane;
            int n = idx >> 2, quad = idx & 3;
            bf16x8 row = *(const bf16x8*)&T[n * 40 + quad * 8];
            *(bf16x8*)(dst + (size_t)n * 32 + quad * 8) = row;
        }
    }
}

// ---------------------------------------------------------------------------
// attn_part: R2-proven loop, n-split x4. 256 thr, grid 1024
// (= 4 b x 64 m-tiles x 4 n-quarters). 16 steps of 64 n each.
// ---------------------------------------------------------------------------
__global__ __launch_bounds__(256) void attn_part(const __hip_bfloat16* __restrict__ qT,
                                                 const __hip_bfloat16* __restrict__ kT,
                                                 const __hip_bfloat16* __restrict__ v,
                                                 const float* __restrict__ scal,
                                                 __hip_bfloat16* __restrict__ Opart,
                                                 float* __restrict__ Lsum) {
    __shared__ __hip_bfloat16 Plds[64 * 72];
    __shared__ float Lp[4][32];

    int t = threadIdx.x;
    int wave = t >> 6, lane = t & 63;
    int lo = lane & 31, hi = lane >> 5;

    // decode: bits[2:0]=x8 (b, m bit5), bits[4:3]=n-quarter, rest = m-tile
    int blk = blockIdx.x;
    int x8 = blk & 7;
    int b = x8 >> 1;
    int nq = (blk >> 3) & 3;
    int m0 = (((x8 & 1) << 5) + (blk >> 5)) << 6;
    int nbase = nq << 10;  // 1024 each

    const __hip_bfloat16* qTb = qT + ((size_t)b << 17);
    const __hip_bfloat16* kTb = kT + ((size_t)b << 17);
    const __hip_bfloat16* vb  = v  + ((size_t)b << 20);

    int mtile_s = wave >> 1, ntile_s = wave & 1;
    int e0w = wave << 6;
    float qkscale = scal[0] * scal[1] * 0.17677669529663687f;

    bf16x8 qf0 = *(const bf16x8*)(qTb + ((size_t)(m0 + mtile_s * 32 + lo)) * 32 + 0  + hi * 8);
    bf16x8 qf1 = *(const bf16x8*)(qTb + ((size_t)(m0 + mtile_s * 32 + lo)) * 32 + 16 + hi * 8);

    f32x16 acc[2][2];
    #pragma unroll
    for (int et = 0; et < 2; et++)
        #pragma unroll
        for (int mt = 0; mt < 2; mt++)
            #pragma unroll
            for (int r = 0; r < 16; r++) acc[et][mt][r] = 0.f;
    float l_acc = 0.f;

    const __hip_bfloat16* krow0 = kTb + (size_t)(ntile_s * 32 + lo) * 32 + hi * 8;
    const __hip_bfloat16* va0b = vb + (size_t)(e0w + lo) * NPOS + hi * 8;
    const __hip_bfloat16* va1b = vb + (size_t)(e0w + 32 + lo) * NPOS + hi * 8;

    for (int s = 0; s < 16; s++) {
        int n0 = nbase + 64 * s;
        const __hip_bfloat16* krow = krow0 + (size_t)n0 * 32;
        bf16x8 kf0 = *(const bf16x8*)(krow);
        bf16x8 kf1 = *(const bf16x8*)(krow + 16);
        f32x16 sv;
        #pragma unroll
        for (int r = 0; r < 16; r++) sv[r] = 0.f;
        sv = __builtin_amdgcn_mfma_f32_32x32x16_bf16(kf0, qf0, sv, 0, 0, 0);
        sv = __builtin_amdgcn_mfma_f32_32x32x16_bf16(kf1, qf1, sv, 0, 0, 0);

        __syncthreads();
        int mrow = mtile_s * 32 + lo;
        #pragma unroll
        for (int g = 0; g < 4; g++) {
            float p0 = __expf(sv[4 * g + 0] * qkscale);
            float p1 = __expf(sv[4 * g + 1] * qkscale);
            float p2 = __expf(sv[4 * g + 2] * qkscale);
            float p3 = __expf(sv[4 * g + 3] * qkscale);
            l_acc += (p0 + p1) + (p2 + p3);
            uint2 pk;
            pk.x = pk2(p0, p1);
            pk.y = pk2(p2, p3);
            int nloc = ntile_s * 32 + 8 * g + 4 * hi;
            *(uint2*)(&Plds[mrow * 72 + nloc]) = pk;
        }
        __syncthreads();

        #pragma unroll
        for (int kc = 0; kc < 4; kc++) {
            bf16x8 pf0 = *(const bf16x8*)(&Plds[(lo)      * 72 + kc * 16 + hi * 8]);
            bf16x8 pf1 = *(const bf16x8*)(&Plds[(32 + lo) * 72 + kc * 16 + hi * 8]);
            bf16x8 vf0 = *(const bf16x8*)(va0b + n0 + kc * 16);
            bf16x8 vf1 = *(const bf16x8*)(va1b + n0 + kc * 16);
            acc[0][0] = __builtin_amdgcn_mfma_f32_32x32x16_bf16(vf0, pf0, acc[0][0], 0, 0, 0);
            acc[0][1] = __builtin_amdgcn_mfma_f32_32x32x16_bf16(vf0, pf1, acc[0][1], 0, 0, 0);
            acc[1][0] = __builtin_amdgcn_mfma_f32_32x32x16_bf16(vf1, pf0, acc[1][0], 0, 0, 0);
            acc[1][1] = __builtin_amdgcn_mfma_f32_32x32x16_bf16(vf1, pf1, acc[1][1], 0, 0, 0);
        }
    }

    float lsum = l_acc + __shfl_xor(l_acc, 32, 64);
    if (lane < 32) Lp[wave][lane] = lsum;
    __syncthreads();
    if (wave == 0) {
        int l2 = lane & 31;
        float Lv = (lane < 32) ? (Lp[0][l2] + Lp[1][l2]) : (Lp[2][l2] + Lp[3][l2]);
        Lsum[(size_t)(nq * 4 + b) * NPOS + m0 + ((lane >> 5) << 5) + l2] = Lv;
    }

    __hip_bfloat16* Ob = Opart + ((size_t)(nq * 4 + b) << 20);
    #pragma unroll
    for (int mt = 0; mt < 2; mt++) {
        int m = m0 + mt * 32 + lo;
        #pragma unroll
        for (int et = 0; et < 2; et++) {
            #pragma unroll
            for (int r = 0; r < 16; r++) {
                int e = e0w + et * 32 + (r & 3) + 8 * (r >> 2) + 4 * hi;
                Ob[(size_t)e * NPOS + m] = __float2bfloat16(acc[et][mt][r]);
            }
        }
    }
}

// ---------------------------------------------------------------------------
// reduce_out: out = x + gamma*sig_v^-1 * (sum_q Oq)/(sum_q Lq). HBM-bound.
// ---------------------------------------------------------------------------
__global__ __launch_bounds__(256) void reduce_out(const float* __restrict__ x,
                                                  const __hip_bfloat16* __restrict__ Opart,
                                                  const float* __restrict__ Lsum,
                                                  const float* __restrict__ scal,
                                                  const float* __restrict__ gam,
                                                  float* __restrict__ out) {
    int b = blockIdx.z, e = blockIdx.y;
    int m4 = (blockIdx.x * 256 + threadIdx.x) * 4;
    float gs = gam[0] * scal[2];

    size_t o = ((size_t)b << 20) + (size_t)e * NPOS + m4;
    float4 xv = *(const float4*)(x + o);

    float o0 = 0.f, o1 = 0.f, o2 = 0.f, o3 = 0.f;
    float l0 = 0.f, l1 = 0.f, l2 = 0.f, l3 = 0.f;
    #pragma unroll
    for (int q = 0; q < 4; q++) {
        int sl = q * 4 + b;
        ushort4 a = *(const ushort4*)(Opart + ((size_t)sl << 20) + (size_t)e * NPOS + m4);
        float4 L = *(const float4*)(Lsum + (size_t)sl * NPOS + m4);
        o0 += b2f(a.x); o1 += b2f(a.y); o2 += b2f(a.z); o3 += b2f(a.w);
        l0 += L.x; l1 += L.y; l2 += L.z; l3 += L.w;
    }

    float4 r;
    r.x = xv.x + gs * o0 / l0;
    r.y = xv.y + gs * o1 / l1;
    r.z = xv.z + gs * o2 / l2;
    r.w = xv.w + gs * o3 / l3;
    *(float4*)(out + o) = r;
}

// ---------------------------------------------------------------------------
extern "C" void kernel_launch(void* const* d_in, const int* in_sizes, int n_in,
                              void* d_out, int out_size, void* d_ws, size_t ws_size,
                              hipStream_t stream) {
    const float* x     = (const float*)d_in[0];
    const float* wq    = (const float*)d_in[1];
    const float* wk    = (const float*)d_in[2];
    const float* wv    = (const float*)d_in[3];
    const float* gamma = (const float*)d_in[4];
    float* out = (float*)d_out;

    char* wsb = (char*)d_ws;
    float* scal = (float*)wsb;                           // 256 B
    __hip_bfloat16* qT = (__hip_bfloat16*)(wsb + 256);   // 1 MB
    __hip_bfloat16* kT = qT + ((size_t)4 << 17);         // 1 MB
    __hip_bfloat16* vp = kT + ((size_t)4 << 17);         // 8 MB
    __hip_bfloat16* Opart = vp + ((size_t)4 << 20);      // 32 MB (16 slices x 2MB)
    float* Lsum = (float*)(Opart + ((size_t)16 << 20));  // 256 KB

    proj_sigma<<<dim3(65, 4), 512, 0, stream>>>(x, wq, wk, wv, qT, kT, vp, scal);
    attn_part<<<1024, 256, 0, stream>>>(qT, kT, vp, scal, Opart, Lsum);
    reduce_out<<<dim3(4, 256, 4), 256, 0, stream>>>(x, Opart, Lsum, scal, gamma, out);
}